// Round 7
// baseline (132.096 us; speedup 1.0000x reference)
//
#include <hip/hip_runtime.h>

typedef unsigned int u32;
typedef unsigned short u16;
typedef __attribute__((ext_vector_type(8))) short bf16x8;
typedef __attribute__((ext_vector_type(8))) u16 u16x8;
typedef __attribute__((ext_vector_type(4))) u16 u16x4;
typedef __attribute__((ext_vector_type(4))) float f32x4;
typedef __attribute__((ext_vector_type(2))) u32 u32x2;

#define AS1 __attribute__((address_space(1)))
#define AS3 __attribute__((address_space(3)))

__device__ __forceinline__ void gload_lds16(const void* g, void* l) {
  __builtin_amdgcn_global_load_lds((const AS1 u32*)g, (AS3 u32*)l, 16, 0, 0);
}

__device__ __forceinline__ u16 f2bf(float f) {
  union { float f; u32 u; } x; x.f = f;
  u32 u = x.u;
  return (u16)((u + 0x7fffu + ((u >> 16) & 1u)) >> 16);
}

__device__ __forceinline__ u32 cvt_pk_bf16(float lo, float hi) {
  u32 r;
  asm("v_cvt_pk_bf16_f32 %0, %1, %2" : "=v"(r) : "v"(lo), "v"(hi));
  return r;
}

// ---------------- convert fp32 -> bf16 (q,k,v,Wq,Wk,Wv,Wo packed contiguously) ---------
__global__ __launch_bounds__(256) void convert_all(
    const float* __restrict__ q, const float* __restrict__ k, const float* __restrict__ v,
    const float* __restrict__ wq, const float* __restrict__ wk,
    const float* __restrict__ wv, const float* __restrict__ wo,
    u16* __restrict__ dst)
{
  int b = blockIdx.x, t = threadIdx.x;
  const float* sp; size_t lb;
  if (b < 6144) {
    sp = (b < 2048) ? q : ((b < 4096) ? k : v);
    lb = (size_t)(b & 2047) * 2048;
  } else {
    int w = (b - 6144) >> 9;
    sp = (w == 0) ? wq : ((w == 1) ? wk : ((w == 2) ? wv : wo));
    lb = (size_t)((b - 6144) & 511) * 2048;
  }
  lb += (size_t)t * 8;
  f32x4 f0 = *(const f32x4*)(sp + lb);
  f32x4 f1 = *(const f32x4*)(sp + lb + 4);
  u16x8 o;
  o[0]=f2bf(f0[0]); o[1]=f2bf(f0[1]); o[2]=f2bf(f0[2]); o[3]=f2bf(f0[3]);
  o[4]=f2bf(f1[0]); o[5]=f2bf(f1[1]); o[6]=f2bf(f1[2]); o[7]=f2bf(f1[3]);
  *(u16x8*)(dst + (size_t)b*2048 + (size_t)t*8) = o;
}

// ---------------- fused QKV GEMM, 128x128 tile (m97 structure) -------------------------
// Q,K -> Cqk[4096][2048] interleaved (Q at +0, K at +1024).
// V   -> VT[b][h][dh][s] transposed bf16 (packed 8B stores along s).
__global__ __launch_bounds__(256) void gemm_qkv(
    const u16* __restrict__ Xall,   // [3][4096][1024] bf16 (q,k,v)
    const u16* __restrict__ Wall,   // [3][1024][1024] bf16 (Wq,Wk,Wv)
    const float* __restrict__ bq, const float* __restrict__ bk, const float* __restrict__ bv,
    u16* __restrict__ Cqk, u16* __restrict__ VT)
{
  __shared__ __align__(16) u16 As[128*64];
  __shared__ __align__(16) u16 Bs[128*64];
  const int t = threadIdx.x;
  const int wid = t >> 6, l = t & 63;
  const int l4 = l >> 4, l15 = l & 15;
  const int bx = blockIdx.x;
  const int which = bx >> 3;          // 8 col-tiles of 128 per which
  const int n0 = (bx & 7) * 128;
  const u16* A  = Xall + (size_t)which * 4194304;
  const u16* Bw = Wall + (size_t)which * 1048576;
  const float* bias = (which == 0) ? bq : ((which == 1) ? bk : bv);
  const int m0 = blockIdx.y * 128;
  const int wr = wid >> 1, wc = wid & 1;
  const int arow = t >> 3, achk = t & 7;

  f32x4 acc[4][4] = {};

  for (int k0 = 0; k0 < 1024; k0 += 64) {
    __syncthreads();
#pragma unroll
    for (int i = 0; i < 4; ++i) {
      int row = i*32 + arow;
      gload_lds16(A + (size_t)(m0+row)*1024 + k0 + ((achk ^ (row&7)) << 3),
                  &As[i*2048 + wid*512]);
    }
#pragma unroll
    for (int i = 0; i < 4; ++i) {
      int row = i*32 + arow;
      gload_lds16(Bw + (size_t)(n0+row)*1024 + k0 + ((achk ^ (row&7)) << 3),
                  &Bs[i*2048 + wid*512]);
    }
    __syncthreads();
#pragma unroll
    for (int kh = 0; kh < 2; ++kh) {
      bf16x8 af[4], bf[4];
#pragma unroll
      for (int mf = 0; mf < 4; ++mf) {
        int row = wr*64 + mf*16 + l15;
        int ch = (kh*4 + l4) ^ (row & 7);
        af[mf] = *(const bf16x8*)&As[row*64 + ch*8];
      }
#pragma unroll
      for (int nf = 0; nf < 4; ++nf) {
        int row = wc*64 + nf*16 + l15;
        int ch = (kh*4 + l4) ^ (row & 7);
        bf[nf] = *(const bf16x8*)&Bs[row*64 + ch*8];
      }
#pragma unroll
      for (int mf = 0; mf < 4; ++mf)
#pragma unroll
        for (int nf = 0; nf < 4; ++nf)
          acc[mf][nf] = __builtin_amdgcn_mfma_f32_16x16x32_bf16(af[mf], bf[nf], acc[mf][nf], 0, 0, 0);
    }
  }
  if (which < 2) {
#pragma unroll
    for (int mf = 0; mf < 4; ++mf)
#pragma unroll
      for (int nf = 0; nf < 4; ++nf) {
        int row = m0 + wr*64 + mf*16 + l4*4;
        int col = n0 + wc*64 + nf*16 + l15;
        float bv = bias[col];
        int colg = which*1024 + col;
#pragma unroll
        for (int r = 0; r < 4; ++r)
          Cqk[(size_t)(row+r)*2048 + colg] = f2bf(acc[mf][nf][r] + bv);
      }
  } else {
#pragma unroll
    for (int mf = 0; mf < 4; ++mf)
#pragma unroll
      for (int nf = 0; nf < 4; ++nf) {
        int row = m0 + wr*64 + mf*16 + l4*4;
        int col = n0 + wc*64 + nf*16 + l15;
        float bv = bias[col];
        int bb = row >> 11, s = row & 2047;
        int hh = col >> 6, dh = col & 63;
        u16x4 pk;
#pragma unroll
        for (int r = 0; r < 4; ++r) pk[r] = f2bf(acc[mf][nf][r] + bv);
        *(u16x4*)&VT[((size_t)(((bb<<4)+hh)<<6) + dh)*2048 + s] = pk;
      }
  }
}

// ---------------- GEMM: out = AO * Wo^T + bo, fp32 out --------------------------------
__global__ __launch_bounds__(256) void gemm_out(
    const u16* __restrict__ A, const u16* __restrict__ Bw,
    const float* __restrict__ bias, float* __restrict__ C)
{
  __shared__ __align__(16) u16 As[128*64];
  __shared__ __align__(16) u16 Bs[64*64];
  const int t = threadIdx.x;
  const int wid = t >> 6, l = t & 63;
  const int l4 = l >> 4, l15 = l & 15;
  const int m0 = blockIdx.y * 128, n0 = blockIdx.x * 64;
  const int wr = wid >> 1, wc = wid & 1;
  const int arow = t >> 3, achk = t & 7;

  f32x4 acc[4][2] = {};

  for (int k0 = 0; k0 < 1024; k0 += 64) {
    __syncthreads();
#pragma unroll
    for (int i = 0; i < 4; ++i) {
      int row = i*32 + arow;
      gload_lds16(A + (size_t)(m0+row)*1024 + k0 + ((achk ^ (row&7)) << 3),
                  &As[i*2048 + wid*512]);
    }
#pragma unroll
    for (int i = 0; i < 2; ++i) {
      int row = i*32 + arow;
      gload_lds16(Bw + (size_t)(n0+row)*1024 + k0 + ((achk ^ (row&7)) << 3),
                  &Bs[i*2048 + wid*512]);
    }
    __syncthreads();
#pragma unroll
    for (int kh = 0; kh < 2; ++kh) {
      bf16x8 af[4], bf[2];
#pragma unroll
      for (int mf = 0; mf < 4; ++mf) {
        int row = wr*64 + mf*16 + l15;
        int ch = (kh*4 + l4) ^ (row & 7);
        af[mf] = *(const bf16x8*)&As[row*64 + ch*8];
      }
#pragma unroll
      for (int nf = 0; nf < 2; ++nf) {
        int row = wc*32 + nf*16 + l15;
        int ch = (kh*4 + l4) ^ (row & 7);
        bf[nf] = *(const bf16x8*)&Bs[row*64 + ch*8];
      }
#pragma unroll
      for (int mf = 0; mf < 4; ++mf)
#pragma unroll
        for (int nf = 0; nf < 2; ++nf)
          acc[mf][nf] = __builtin_amdgcn_mfma_f32_16x16x32_bf16(af[mf], bf[nf], acc[mf][nf], 0, 0, 0);
    }
  }
#pragma unroll
  for (int mf = 0; mf < 4; ++mf)
#pragma unroll
    for (int nf = 0; nf < 2; ++nf) {
      int row = m0 + wr*64 + mf*16 + l4*4;
      int col = n0 + wc*32 + nf*16 + l15;
      float bv = bias[col];
#pragma unroll
      for (int r = 0; r < 4; ++r)
        C[(size_t)(row+r)*1024 + col] = acc[mf][nf][r] + bv;
    }
}

// ---------------- causal flash attention, split-KV, DH=64, QBLK=64, KVBLK=64 -----------
// 1024 blocks (1D, XCD-chunked): (p,s=0) = q-tile p final + q-tile 31-p partial (KV
// 0..15-p); (p,s=1) = q-tile 31-p partial (KV 16-p..31-p). Uniform 16-17 iters/block.
// Swapped QK^T AND swapped PV: scores and O^T both have q = lane&15 -> softmax, corr,
// li, normalize all lane-local (no cross-lane relayout at all).
__device__ __forceinline__ void stage_kv(u16* lds, const u16* Kt, const u16* Vt,
                                         int buf, int wid) {
#pragma unroll
  for (int ii = 0; ii < 2; ++ii)
    gload_lds16(Kt + (size_t)ii*32*2048, &lds[4096 + buf*4096 + ii*2048 + wid*512]);
#pragma unroll
  for (int ii = 0; ii < 2; ++ii)
    gload_lds16(Vt + (size_t)ii*32*2048, &lds[12288 + buf*4096 + ii*2048 + wid*512]);
}

__device__ __forceinline__ void attn_phase(
    u16* lds, const u16* Qg, const u16* Ka, const u16* Va,
    int q0, int kt0, int nkv, bool maskLast,
    int wid, int g, int c, int arow, int achk, int pbase, int cs,
    float& MI, float& LI, f32x4 (&o)[4])
{
  const float SC = 0.18033688f;  // (1/8) * log2(e)
  // stage Q tile [64][64] swizzled
#pragma unroll
  for (int i = 0; i < 2; ++i) {
    int row = i*32 + arow;
    gload_lds16(Qg + (size_t)(q0+row)*2048 + ((achk ^ (row&7)) << 3),
                &lds[i*2048 + wid*512]);
  }
  const u16* Kt = Ka + (size_t)kt0 * (64*2048);
  const u16* Vt = Va + kt0 * 64;
  stage_kv(lds, Kt, Vt, 0, wid);
  asm volatile("s_waitcnt vmcnt(0)" ::: "memory");
  __builtin_amdgcn_s_barrier();
  __builtin_amdgcn_sched_barrier(0);

  bf16x8 qf[2];
#pragma unroll
  for (int kh = 0; kh < 2; ++kh) {
    int row = wid*16 + c;
    int ch = (kh*4 + g) ^ (row & 7);
    qf[kh] = *(const bf16x8*)&lds[row*64 + ch*8];
  }

  float mi = -INFINITY, li = 0.f;
#pragma unroll
  for (int df = 0; df < 4; ++df) o[df] = f32x4{0.f, 0.f, 0.f, 0.f};

  for (int i = 0; i < nkv; ++i) {
    if (i + 1 < nkv) {
      Kt += 64*2048; Vt += 64;
      stage_kv(lds, Kt, Vt, (i+1)&1, wid);
    }
    const u16* Kb = &lds[4096  + (i&1)*4096];
    const u16* Vb = &lds[12288 + (i&1)*4096];

    // QK^T swapped: lane holds q = c, k = 16nf + 4g + r
    f32x4 sT[4] = {};
#pragma unroll
    for (int kh = 0; kh < 2; ++kh) {
      bf16x8 kf[4];
#pragma unroll
      for (int nf = 0; nf < 4; ++nf) {
        int row = nf*16 + c;
        int ch = (kh*4 + g) ^ (c & 7);
        kf[nf] = *(const bf16x8*)&Kb[row*64 + ch*8];
      }
#pragma unroll
      for (int nf = 0; nf < 4; ++nf)
        sT[nf] = __builtin_amdgcn_mfma_f32_16x16x32_bf16(kf[nf], qf[kh], sT[nf], 0,0,0);
    }

    if (maskLast && i == nkv - 1) {   // diagonal causal mask
#pragma unroll
      for (int nf = 0; nf < 4; ++nf)
#pragma unroll
        for (int r = 0; r < 4; ++r)
          if (nf*16 + g*4 + r > wid*16 + c) sT[nf][r] = -INFINITY;
    }

    // online softmax: lane-local reduce + 2 shuffles (k spread over groups g)
    float mx = fmaxf(fmaxf(sT[0][0], sT[0][1]), fmaxf(sT[0][2], sT[0][3]));
#pragma unroll
    for (int nf = 1; nf < 4; ++nf)
      mx = fmaxf(mx, fmaxf(fmaxf(sT[nf][0], sT[nf][1]), fmaxf(sT[nf][2], sT[nf][3])));
    mx = fmaxf(mx, __shfl_xor(mx, 16, 64));
    mx = fmaxf(mx, __shfl_xor(mx, 32, 64));
    float mn = fmaxf(mi, mx * SC);
    float corr = exp2f(mi - mn);
    float sum = 0.f;
#pragma unroll
    for (int nf = 0; nf < 4; ++nf)
#pragma unroll
      for (int r = 0; r < 4; ++r) {
        float pv = exp2f(fmaf(sT[nf][r], SC, -mn));
        sT[nf][r] = pv;
        sum += pv;
      }
    sum += __shfl_xor(sum, 16, 64);
    sum += __shfl_xor(sum, 32, 64);
    li = li * corr + sum;
    mi = mn;

    // O^T rescale: corr is lane-local (q = c for both sT and o)
#pragma unroll
    for (int df = 0; df < 4; ++df) {
      o[df][0] *= corr; o[df][1] *= corr;
      o[df][2] *= corr; o[df][3] *= corr;
    }

    // P -> LDS (wave-private), packed bf16 via cvt_pk + b64 writes
#pragma unroll
    for (int nf = 0; nf < 4; ++nf) {
      u32x2 w;
      w[0] = cvt_pk_bf16(sT[nf][0], sT[nf][1]);
      w[1] = cvt_pk_bf16(sT[nf][2], sT[nf][3]);
      int ch = (2*nf + (g >> 1)) ^ cs;
      *(u32x2*)&lds[pbase + c*64 + ch*8 + (g & 1)*4] = w;
    }
    asm volatile("s_waitcnt lgkmcnt(0)" ::: "memory");
    __builtin_amdgcn_sched_barrier(0);

    // PV swapped: o[df] = V^T-frag x P-frag -> O^T[d = df*16+4g+r][q = c]
#pragma unroll
    for (int kh = 0; kh < 2; ++kh) {
      bf16x8 pfr, vf[4];
      {
        int ch = (kh*4 + g) ^ cs;
        pfr = *(const bf16x8*)&lds[pbase + c*64 + ch*8];
      }
#pragma unroll
      for (int df = 0; df < 4; ++df) {
        int d = df*16 + c;
        int ch = (kh*4 + g) ^ (d & 7);
        vf[df] = *(const bf16x8*)&Vb[d*64 + ch*8];
      }
#pragma unroll
      for (int df = 0; df < 4; ++df)
        o[df] = __builtin_amdgcn_mfma_f32_16x16x32_bf16(vf[df], pfr, o[df], 0,0,0);
    }

    asm volatile("s_waitcnt vmcnt(0)" ::: "memory");  // next K/V tile landed
    __builtin_amdgcn_s_barrier();                     // all done reading cur bufs
    __builtin_amdgcn_sched_barrier(0);
  }
  MI = mi; LI = li;
}

__device__ __forceinline__ void store_partial(
    float* __restrict__ part, int slot, int s,
    int wid, int g, int c, float mi, float li, const f32x4 (&o)[4])
{
  float* po = part + (size_t)(slot*2 + s) * 4224;
  int q = wid*16 + c;
#pragma unroll
  for (int df = 0; df < 4; ++df)
    *(f32x4*)&po[q*64 + df*16 + g*4] = o[df];
  if (g == 0) { po[4096 + q] = mi; po[4160 + q] = li; }
}

__global__ __launch_bounds__(256, 4) void attn_fwd(
    const u16* __restrict__ QK, const u16* __restrict__ VT,
    u16* __restrict__ AO, float* __restrict__ part)
{
  // u16 units: [0,4096) Q staging / per-wave P; [4096,12288) K dbuf; [12288,20480) V dbuf
  __shared__ __align__(16) u16 lds[20480];
  const int t = threadIdx.x;
  const int wid = t >> 6, l = t & 63;
  const int g = l >> 4, c = l & 15;
  // XCD-chunked decode: id%8 round-robin -> each XCD gets 128 consecutive logical ids
  // = 4 (b,h) groups (KV working set 2MB < 4MB L2/XCD)
  const int u = blockIdx.x;
  const int lid = (u & 7) * 128 + (u >> 3);
  const int gx = lid & 31, h = (lid >> 5) & 15, b = lid >> 9;
  const int p = gx >> 1, s = gx & 1;
  const u16* Qg  = QK + (size_t)b * 2048 * 2048 + (size_t)h * 64;
  const u16* Kg  = Qg + 1024;
  const u16* VTg = VT + (size_t)(((b << 4) + h) << 6) * 2048;
  const int arow = t >> 3, achk = t & 7;
  const int pbase = wid * 1024;
  const int cs = (c & 7) ^ ((c >> 3) << 2);
  const u16* Ka = Kg  + (size_t)arow*2048 + ((achk ^ (arow & 7)) << 3);
  const u16* Va = VTg + (size_t)arow*2048 + ((achk ^ (arow & 7)) << 3);
  const int slot = ((b*16 + h)*16 + p);

  float mi, li; f32x4 o[4];

  if (s == 0) {
    // phase A: q-tile p, KV 0..p, final output
    attn_phase(lds, Qg, Ka, Va, p*64, 0, p+1, true,
               wid, g, c, arow, achk, pbase, cs, mi, li, o);
    {
      float nr = 1.f / li;                  // lane-local (q = c)
      int row = p*64 + wid*16 + c;
      size_t rb = ((size_t)b*2048 + row)*1024 + h*64;
#pragma unroll
      for (int df = 0; df < 4; ++df) {
        u16x4 pk;
        pk[0] = f2bf(o[df][0] * nr); pk[1] = f2bf(o[df][1] * nr);
        pk[2] = f2bf(o[df][2] * nr); pk[3] = f2bf(o[df][3] * nr);
        *(u16x4*)&AO[rb + df*16 + g*4] = pk;
      }
    }
    // phase B: q-tile 31-p, KV tiles 0..15-p, partial slot 0
    attn_phase(lds, Qg, Ka, Va, (31-p)*64, 0, 16-p, false,
               wid, g, c, arow, achk, pbase, cs, mi, li, o);
    store_partial(part, slot, 0, wid, g, c, mi, li, o);
  } else {
    // q-tile 31-p, KV tiles 16-p..31-p (incl. diagonal), partial slot 1
    attn_phase(lds, Qg, Ka, Va, (31-p)*64, 16-p, 16, true,
               wid, g, c, arow, achk, pbase, cs, mi, li, o);
    store_partial(part, slot, 1, wid, g, c, mi, li, o);
  }
}

// ---------------- merge the two partials of q-tiles 16..31 -----------------------------
__global__ __launch_bounds__(256) void attn_merge(
    const float* __restrict__ part, u16* __restrict__ AO)
{
  int slot = blockIdx.x;            // ((b*16+h)*16+p)
  int p = slot & 15;
  int h = (slot >> 4) & 15;
  int b = slot >> 8;
  const float* p0 = part + (size_t)slot * 8448;
  const float* p1 = p0 + 4224;
  int t = threadIdx.x;
  int r = t >> 2, c0 = (t & 3) * 16;
  float m0 = p0[4096 + r], m1 = p1[4096 + r];
  float l0 = p0[4160 + r], l1 = p1[4160 + r];
  float m = fmaxf(m0, m1);
  float e0 = exp2f(m0 - m), e1 = exp2f(m1 - m);
  float rl = 1.f / (l0*e0 + l1*e1);
  e0 *= rl; e1 *= rl;
  const f32x4* a0 = (const f32x4*)(p0 + r*64 + c0);
  const f32x4* a1 = (const f32x4*)(p1 + r*64 + c0);
  u16x8 w0, w1;
#pragma unroll
  for (int q4 = 0; q4 < 4; ++q4) {
    f32x4 x = a0[q4], y = a1[q4];
#pragma unroll
    for (int j = 0; j < 4; ++j) {
      u16 bf = f2bf(x[j]*e0 + y[j]*e1);
      if (q4 < 2) w0[q4*4+j] = bf; else w1[(q4-2)*4+j] = bf;
    }
  }
  int qrow = (31 - p)*64 + r;
  size_t ab = ((size_t)b*2048 + qrow)*1024 + h*64 + c0;
  *(u16x8*)&AO[ab]     = w0;
  *(u16x8*)&AO[ab + 8] = w1;
}

// ---------------------------------------------------------------------------------------
extern "C" void kernel_launch(void* const* d_in, const int* in_sizes, int n_in,
                              void* d_out, int out_size, void* d_ws, size_t ws_size,
                              hipStream_t stream)
{
  const float* q  = (const float*)d_in[0];
  const float* k  = (const float*)d_in[1];
  const float* v  = (const float*)d_in[2];
  // d_in[3] = mask (causal tril; applied analytically)
  const float* Wq = (const float*)d_in[4];
  const float* bq = (const float*)d_in[5];
  const float* Wk = (const float*)d_in[6];
  const float* bk = (const float*)d_in[7];
  const float* Wv = (const float*)d_in[8];
  const float* bv = (const float*)d_in[9];
  const float* Wo = (const float*)d_in[10];
  const float* bo = (const float*)d_in[11];
  float* out = (float*)d_out;

  u16* ws   = (u16*)d_ws;
  u16* qb   = ws;                 // [3][4096][1024] bf16 inputs (dead after gemm_qkv;
                                  //  reused as f32 partial buffer by attn)
  u16* Wqb  = ws + 12582912;      // [3][1024][1024] bf16 weights (Wq,Wk,Wv)
  u16* Wob  = ws + 15728640;      // [1024][1024]
  u16* QKp  = ws + 16777216;      // [4096][2048]  (Q | K)
  u16* VTp  = ws + 25165824;      // [2][16][64][2048]  V transposed
  u16* AO   = ws + 29360128;      // [4096][1024]   (total = 64 MB exactly)

  convert_all<<<8192, 256, 0, stream>>>(q, k, v, Wq, Wk, Wv, Wo, qb);

  dim3 gq(24, 32);
  gemm_qkv<<<gq, 256, 0, stream>>>(qb, Wqb, bq, bk, bv, QKp, VTp);

  attn_fwd<<<1024, 256, 0, stream>>>(QKp, VTp, AO, (float*)d_ws);

  attn_merge<<<512, 256, 0, stream>>>((const float*)d_ws, AO);

  dim3 g1(16, 32);
  gemm_out<<<g1, 256, 0, stream>>>(AO, Wob, bo, out);
}

// Round 8
// 114.710 us; speedup vs baseline: 1.1516x; 1.1516x over previous
//
#include <hip/hip_runtime.h>

typedef unsigned int u32;
typedef unsigned short u16;
typedef __attribute__((ext_vector_type(8))) short bf16x8;
typedef __attribute__((ext_vector_type(8))) u16 u16x8;
typedef __attribute__((ext_vector_type(4))) u16 u16x4;
typedef __attribute__((ext_vector_type(4))) float f32x4;
typedef __attribute__((ext_vector_type(2))) u32 u32x2;

#define AS1 __attribute__((address_space(1)))
#define AS3 __attribute__((address_space(3)))

__device__ __forceinline__ void gload_lds16(const void* g, void* l) {
  __builtin_amdgcn_global_load_lds((const AS1 u32*)g, (AS3 u32*)l, 16, 0, 0);
}

__device__ __forceinline__ u16 f2bf(float f) {
  union { float f; u32 u; } x; x.f = f;
  u32 u = x.u;
  return (u16)((u + 0x7fffu + ((u >> 16) & 1u)) >> 16);
}

__device__ __forceinline__ u32 cvt_pk_bf16(float lo, float hi) {
  u32 r;
  asm("v_cvt_pk_bf16_f32 %0, %1, %2" : "=v"(r) : "v"(lo), "v"(hi));
  return r;
}

__device__ __forceinline__ float fexp2(float x) {
  float r;
  asm("v_exp_f32 %0, %1" : "=v"(r) : "v"(x));
  return r;
}

// ---------------- convert fp32 -> bf16 (q,k,v,Wq,Wk,Wv,Wo packed contiguously) ---------
__global__ __launch_bounds__(256) void convert_all(
    const float* __restrict__ q, const float* __restrict__ k, const float* __restrict__ v,
    const float* __restrict__ wq, const float* __restrict__ wk,
    const float* __restrict__ wv, const float* __restrict__ wo,
    u16* __restrict__ dst)
{
  int b = blockIdx.x, t = threadIdx.x;
  const float* sp; size_t lb;
  if (b < 6144) {
    sp = (b < 2048) ? q : ((b < 4096) ? k : v);
    lb = (size_t)(b & 2047) * 2048;
  } else {
    int w = (b - 6144) >> 9;
    sp = (w == 0) ? wq : ((w == 1) ? wk : ((w == 2) ? wv : wo));
    lb = (size_t)((b - 6144) & 511) * 2048;
  }
  lb += (size_t)t * 8;
  f32x4 f0 = *(const f32x4*)(sp + lb);
  f32x4 f1 = *(const f32x4*)(sp + lb + 4);
  u16x8 o;
  o[0]=f2bf(f0[0]); o[1]=f2bf(f0[1]); o[2]=f2bf(f0[2]); o[3]=f2bf(f0[3]);
  o[4]=f2bf(f1[0]); o[5]=f2bf(f1[1]); o[6]=f2bf(f1[2]); o[7]=f2bf(f1[3]);
  *(u16x8*)(dst + (size_t)b*2048 + (size_t)t*8) = o;
}

// ---------------- fused QKV GEMM, 256x256 tile, BK=32, ring-3 deep pipeline ------------
// 512 threads = 8 waves (2x4). Per-wave output 128x64 (acc[8][4]). LDS 96 KB (3 ring
// buffers x (A 16KB + B 16KB)). stage(t+2) targets a buffer no wave reads; counted
// vmcnt(4) -> loads stay in flight ~2 K-steps. Grid 192 blocks, XCD-chunked.
// Q,K -> Cqk[4096][2048] interleaved; V -> VT[b][h][dh][s] transposed bf16.
__global__ __launch_bounds__(512, 2) void gemm_qkv(
    const u16* __restrict__ Xall,   // [3][4096][1024] bf16 (q,k,v)
    const u16* __restrict__ Wall,   // [3][1024][1024] bf16 (Wq,Wk,Wv)
    const float* __restrict__ bq, const float* __restrict__ bk, const float* __restrict__ bv,
    u16* __restrict__ Cqk, u16* __restrict__ VT)
{
  __shared__ __align__(16) u16 lds[49152];   // 3 x 16384 u16 (A:[0,8192) B:[8192,16384))
  const int t = threadIdx.x;
  const int w = t >> 6, l = t & 63;
  const int c = l & 15, g = l >> 4;
  // chunked XCD decode: 192 blocks, 24 consecutive lids per XCD (192 % 8 == 0, bijective)
  const int u = blockIdx.x;
  const int lid = (u & 7) * 24 + (u >> 3);
  const int by = lid / 12, rest = lid % 12;
  const int which = rest >> 2, ntl = rest & 3;
  const int m0 = by * 256, n0 = ntl * 256;
  const u16* A  = Xall + (size_t)which * 4194304;
  const u16* Bw = Wall + (size_t)which * 1048576;
  const int wr = w >> 2, wc = w & 3;

  // staging map: srow = w*16 + (l>>2), chunk = l&3; two row-passes (+128)
  const int srow = w*16 + (l >> 2);
  const int schk = l & 3;
  const int sswz = (schk ^ (srow & 3) ^ ((srow >> 2) & 3)) << 3;   // pre-swizzled k-offset
  const u16* Asrc0 = A  + (size_t)(m0 + srow)*1024       + sswz;
  const u16* Asrc1 = A  + (size_t)(m0 + 128 + srow)*1024 + sswz;   // (+128 preserves swz)
  const u16* Bsrc0 = Bw + (size_t)(n0 + srow)*1024       + sswz;
  const u16* Bsrc1 = Bw + (size_t)(n0 + 128 + srow)*1024 + sswz;
  const int wbase = w * 512;                                        // u16 units

#define QKV_STAGE(j) do { \
    const int bo_ = ((j) % 3) * 16384; const int ko_ = (j) << 5; \
    gload_lds16(Asrc0 + ko_, &lds[bo_ + wbase]); \
    gload_lds16(Asrc1 + ko_, &lds[bo_ + 4096 + wbase]); \
    gload_lds16(Bsrc0 + ko_, &lds[bo_ + 8192 + wbase]); \
    gload_lds16(Bsrc1 + ko_, &lds[bo_ + 12288 + wbase]); \
  } while (0)

  // frag-read lane offsets (read-side swizzle matches source swizzle)
  const int fswz = (g ^ (c & 3) ^ (c >> 2)) << 3;
  const int abase = (wr*128 + c)*32 + fswz;           // + mf*512
  const int bbase = 8192 + (wc*64 + c)*32 + fswz;     // + nf*512

  f32x4 acc[8][4] = {};

  QKV_STAGE(0);
  QKV_STAGE(1);
  asm volatile("s_waitcnt vmcnt(4)" ::: "memory");   // stage(0) landed
  __builtin_amdgcn_s_barrier();
  __builtin_amdgcn_sched_barrier(0);

#pragma unroll
  for (int tstep = 0; tstep < 32; ++tstep) {
    if (tstep + 2 < 32) QKV_STAGE(tstep + 2);
    const int bo = (tstep % 3) * 16384;
    bf16x8 af[8], bf[4];
#pragma unroll
    for (int mf = 0; mf < 8; ++mf)
      af[mf] = *(const bf16x8*)&lds[bo + abase + mf*512];
#pragma unroll
    for (int nf = 0; nf < 4; ++nf)
      bf[nf] = *(const bf16x8*)&lds[bo + bbase + nf*512];
    __builtin_amdgcn_s_setprio(1);
#pragma unroll
    for (int mf = 0; mf < 8; ++mf)
#pragma unroll
      for (int nf = 0; nf < 4; ++nf)
        acc[mf][nf] = __builtin_amdgcn_mfma_f32_16x16x32_bf16(af[mf], bf[nf], acc[mf][nf], 0, 0, 0);
    __builtin_amdgcn_s_setprio(0);
    if (tstep + 2 < 32) asm volatile("s_waitcnt vmcnt(4)" ::: "memory");
    else                asm volatile("s_waitcnt vmcnt(0)" ::: "memory");
    __builtin_amdgcn_s_barrier();
    __builtin_amdgcn_sched_barrier(0);
  }
#undef QKV_STAGE

  const float* bias = (which == 0) ? bq : ((which == 1) ? bk : bv);
  if (which < 2) {
#pragma unroll
    for (int mf = 0; mf < 8; ++mf)
#pragma unroll
      for (int nf = 0; nf < 4; ++nf) {
        int row = m0 + wr*128 + mf*16 + g*4;
        int col = n0 + wc*64 + nf*16 + c;
        float bv_ = bias[col];
        int colg = which*1024 + col;
#pragma unroll
        for (int r = 0; r < 4; ++r)
          Cqk[(size_t)(row+r)*2048 + colg] = f2bf(acc[mf][nf][r] + bv_);
      }
  } else {
#pragma unroll
    for (int mf = 0; mf < 8; ++mf)
#pragma unroll
      for (int nf = 0; nf < 4; ++nf) {
        int row = m0 + wr*128 + mf*16 + g*4;
        int col = n0 + wc*64 + nf*16 + c;
        float bv_ = bias[col];
        int bb2 = row >> 11, s = row & 2047;
        int hh = col >> 6, dh = col & 63;
        u16x4 pk;
#pragma unroll
        for (int r = 0; r < 4; ++r) pk[r] = f2bf(acc[mf][nf][r] + bv_);
        *(u16x4*)&VT[((size_t)(((bb2<<4)+hh)<<6) + dh)*2048 + s] = pk;
      }
  }
}

// ---------------- GEMM: out = AO * Wo^T + bo, fp32 out --------------------------------
__global__ __launch_bounds__(256) void gemm_out(
    const u16* __restrict__ A, const u16* __restrict__ Bw,
    const float* __restrict__ bias, float* __restrict__ C)
{
  __shared__ __align__(16) u16 As[128*64];
  __shared__ __align__(16) u16 Bs[64*64];
  const int t = threadIdx.x;
  const int wid = t >> 6, l = t & 63;
  const int l4 = l >> 4, l15 = l & 15;
  const int m0 = blockIdx.y * 128, n0 = blockIdx.x * 64;
  const int wr = wid >> 1, wc = wid & 1;
  const int arow = t >> 3, achk = t & 7;

  f32x4 acc[4][2] = {};

  for (int k0 = 0; k0 < 1024; k0 += 64) {
    __syncthreads();
#pragma unroll
    for (int i = 0; i < 4; ++i) {
      int row = i*32 + arow;
      gload_lds16(A + (size_t)(m0+row)*1024 + k0 + ((achk ^ (row&7)) << 3),
                  &As[i*2048 + wid*512]);
    }
#pragma unroll
    for (int i = 0; i < 2; ++i) {
      int row = i*32 + arow;
      gload_lds16(Bw + (size_t)(n0+row)*1024 + k0 + ((achk ^ (row&7)) << 3),
                  &Bs[i*2048 + wid*512]);
    }
    __syncthreads();
#pragma unroll
    for (int kh = 0; kh < 2; ++kh) {
      bf16x8 af[4], bf[2];
#pragma unroll
      for (int mf = 0; mf < 4; ++mf) {
        int row = wr*64 + mf*16 + l15;
        int ch = (kh*4 + l4) ^ (row & 7);
        af[mf] = *(const bf16x8*)&As[row*64 + ch*8];
      }
#pragma unroll
      for (int nf = 0; nf < 2; ++nf) {
        int row = wc*32 + nf*16 + l15;
        int ch = (kh*4 + l4) ^ (row & 7);
        bf[nf] = *(const bf16x8*)&Bs[row*64 + ch*8];
      }
#pragma unroll
      for (int mf = 0; mf < 4; ++mf)
#pragma unroll
        for (int nf = 0; nf < 2; ++nf)
          acc[mf][nf] = __builtin_amdgcn_mfma_f32_16x16x32_bf16(af[mf], bf[nf], acc[mf][nf], 0, 0, 0);
    }
  }
#pragma unroll
  for (int mf = 0; mf < 4; ++mf)
#pragma unroll
    for (int nf = 0; nf < 2; ++nf) {
      int row = m0 + wr*64 + mf*16 + l4*4;
      int col = n0 + wc*32 + nf*16 + l15;
      float bv = bias[col];
#pragma unroll
      for (int r = 0; r < 4; ++r)
        C[(size_t)(row+r)*1024 + col] = acc[mf][nf][r] + bv;
    }
}

// ---------------- causal flash attention, split-KV, DH=64, QBLK=64, KVBLK=64 -----------
// 1024 blocks (XCD-chunked): (p,s=0) = q-tile p final + q-tile 31-p partial (KV 0..15-p);
// (p,s=1) = q-tile 31-p partial (KV 16-p..31-p). Uniform 16-17 iters/block.
// Swapped QK^T and swapped PV -> softmax/corr/normalize fully lane-local.
__device__ __forceinline__ void stage_kv(u16* lds, const u16* Kt, const u16* Vt,
                                         int buf, int wid) {
#pragma unroll
  for (int ii = 0; ii < 2; ++ii)
    gload_lds16(Kt + (size_t)ii*32*2048, &lds[4096 + buf*4096 + ii*2048 + wid*512]);
#pragma unroll
  for (int ii = 0; ii < 2; ++ii)
    gload_lds16(Vt + (size_t)ii*32*2048, &lds[12288 + buf*4096 + ii*2048 + wid*512]);
}

__device__ __forceinline__ void attn_phase(
    u16* lds, const u16* Qg, const u16* Ka, const u16* Va,
    int q0, int kt0, int nkv, bool maskLast,
    int wid, int g, int c, int arow, int achk, int pbase, int cs,
    float& MI, float& LI, f32x4 (&o)[4])
{
  const float SC = 0.18033688f;  // (1/8) * log2(e)
  // stage Q tile [64][64] swizzled
#pragma unroll
  for (int i = 0; i < 2; ++i) {
    int row = i*32 + arow;
    gload_lds16(Qg + (size_t)(q0+row)*2048 + ((achk ^ (row&7)) << 3),
                &lds[i*2048 + wid*512]);
  }
  const u16* Kt = Ka + (size_t)kt0 * (64*2048);
  const u16* Vt = Va + kt0 * 64;
  stage_kv(lds, Kt, Vt, 0, wid);
  asm volatile("s_waitcnt vmcnt(0)" ::: "memory");
  __builtin_amdgcn_s_barrier();
  __builtin_amdgcn_sched_barrier(0);

  bf16x8 qf[2];
#pragma unroll
  for (int kh = 0; kh < 2; ++kh) {
    int row = wid*16 + c;
    int ch = (kh*4 + g) ^ (row & 7);
    qf[kh] = *(const bf16x8*)&lds[row*64 + ch*8];
  }

  float mi = -INFINITY, li = 0.f;
#pragma unroll
  for (int df = 0; df < 4; ++df) o[df] = f32x4{0.f, 0.f, 0.f, 0.f};

  for (int i = 0; i < nkv; ++i) {
    if (i + 1 < nkv) {
      Kt += 64*2048; Vt += 64;
      stage_kv(lds, Kt, Vt, (i+1)&1, wid);
    }
    const u16* Kb = &lds[4096  + (i&1)*4096];
    const u16* Vb = &lds[12288 + (i&1)*4096];

    // QK^T swapped: lane holds q = c, k = 16nf + 4g + r
    f32x4 sT[4] = {};
    __builtin_amdgcn_s_setprio(1);
#pragma unroll
    for (int kh = 0; kh < 2; ++kh) {
      bf16x8 kf[4];
#pragma unroll
      for (int nf = 0; nf < 4; ++nf) {
        int row = nf*16 + c;
        int ch = (kh*4 + g) ^ (c & 7);
        kf[nf] = *(const bf16x8*)&Kb[row*64 + ch*8];
      }
#pragma unroll
      for (int nf = 0; nf < 4; ++nf)
        sT[nf] = __builtin_amdgcn_mfma_f32_16x16x32_bf16(kf[nf], qf[kh], sT[nf], 0,0,0);
    }
    __builtin_amdgcn_s_setprio(0);

    if (maskLast && i == nkv - 1) {   // diagonal causal mask
#pragma unroll
      for (int nf = 0; nf < 4; ++nf)
#pragma unroll
        for (int r = 0; r < 4; ++r)
          if (nf*16 + g*4 + r > wid*16 + c) sT[nf][r] = -INFINITY;
    }

    // online softmax: lane-local reduce + 2 shuffles (k spread over groups g)
    float mx = fmaxf(fmaxf(sT[0][0], sT[0][1]), fmaxf(sT[0][2], sT[0][3]));
#pragma unroll
    for (int nf = 1; nf < 4; ++nf)
      mx = fmaxf(mx, fmaxf(fmaxf(sT[nf][0], sT[nf][1]), fmaxf(sT[nf][2], sT[nf][3])));
    mx = fmaxf(mx, __shfl_xor(mx, 16, 64));
    mx = fmaxf(mx, __shfl_xor(mx, 32, 64));
    float mn = fmaxf(mi, mx * SC);
    float corr = fexp2(mi - mn);
    float sum = 0.f;
#pragma unroll
    for (int nf = 0; nf < 4; ++nf)
#pragma unroll
      for (int r = 0; r < 4; ++r) {
        float pv = fexp2(fmaf(sT[nf][r], SC, -mn));
        sT[nf][r] = pv;
        sum += pv;
      }
    sum += __shfl_xor(sum, 16, 64);
    sum += __shfl_xor(sum, 32, 64);
    li = li * corr + sum;
    mi = mn;

    // O^T rescale: corr is lane-local (q = c for both sT and o)
#pragma unroll
    for (int df = 0; df < 4; ++df) {
      o[df][0] *= corr; o[df][1] *= corr;
      o[df][2] *= corr; o[df][3] *= corr;
    }

    // P -> LDS (wave-private), packed bf16 via cvt_pk + b64 writes
#pragma unroll
    for (int nf = 0; nf < 4; ++nf) {
      u32x2 ww;
      ww[0] = cvt_pk_bf16(sT[nf][0], sT[nf][1]);
      ww[1] = cvt_pk_bf16(sT[nf][2], sT[nf][3]);
      int ch = (2*nf + (g >> 1)) ^ cs;
      *(u32x2*)&lds[pbase + c*64 + ch*8 + (g & 1)*4] = ww;
    }
    asm volatile("s_waitcnt lgkmcnt(0)" ::: "memory");
    __builtin_amdgcn_sched_barrier(0);

    // PV swapped: o[df] = V^T-frag x P-frag -> O^T[d = df*16+4g+r][q = c]
    __builtin_amdgcn_s_setprio(1);
#pragma unroll
    for (int kh = 0; kh < 2; ++kh) {
      bf16x8 pfr, vf[4];
      {
        int ch = (kh*4 + g) ^ cs;
        pfr = *(const bf16x8*)&lds[pbase + c*64 + ch*8];
      }
#pragma unroll
      for (int df = 0; df < 4; ++df) {
        int d = df*16 + c;
        int ch = (kh*4 + g) ^ (d & 7);
        vf[df] = *(const bf16x8*)&Vb[d*64 + ch*8];
      }
#pragma unroll
      for (int df = 0; df < 4; ++df)
        o[df] = __builtin_amdgcn_mfma_f32_16x16x32_bf16(vf[df], pfr, o[df], 0,0,0);
    }
    __builtin_amdgcn_s_setprio(0);

    asm volatile("s_waitcnt vmcnt(0)" ::: "memory");  // next K/V tile landed
    __builtin_amdgcn_s_barrier();                     // all done reading cur bufs
    __builtin_amdgcn_sched_barrier(0);
  }
  MI = mi; LI = li;
}

__device__ __forceinline__ void store_partial(
    float* __restrict__ part, int slot, int s,
    int wid, int g, int c, float mi, float li, const f32x4 (&o)[4])
{
  float* po = part + (size_t)(slot*2 + s) * 4224;
  int q = wid*16 + c;
#pragma unroll
  for (int df = 0; df < 4; ++df)
    *(f32x4*)&po[q*64 + df*16 + g*4] = o[df];
  if (g == 0) { po[4096 + q] = mi; po[4160 + q] = li; }
}

__global__ __launch_bounds__(256, 4) void attn_fwd(
    const u16* __restrict__ QK, const u16* __restrict__ VT,
    u16* __restrict__ AO, float* __restrict__ part)
{
  // u16 units: [0,4096) Q staging / per-wave P; [4096,12288) K dbuf; [12288,20480) V dbuf
  __shared__ __align__(16) u16 lds[20480];
  const int t = threadIdx.x;
  const int wid = t >> 6, l = t & 63;
  const int g = l >> 4, c = l & 15;
  const int u = blockIdx.x;
  const int lid = (u & 7) * 128 + (u >> 3);
  const int gx = lid & 31, h = (lid >> 5) & 15, b = lid >> 9;
  const int p = gx >> 1, s = gx & 1;
  const u16* Qg  = QK + (size_t)b * 2048 * 2048 + (size_t)h * 64;
  const u16* Kg  = Qg + 1024;
  const u16* VTg = VT + (size_t)(((b << 4) + h) << 6) * 2048;
  const int arow = t >> 3, achk = t & 7;
  const int pbase = wid * 1024;
  const int cs = (c & 7) ^ ((c >> 3) << 2);
  const u16* Ka = Kg  + (size_t)arow*2048 + ((achk ^ (arow & 7)) << 3);
  const u16* Va = VTg + (size_t)arow*2048 + ((achk ^ (arow & 7)) << 3);
  const int slot = ((b*16 + h)*16 + p);

  float mi, li; f32x4 o[4];

  if (s == 0) {
    attn_phase(lds, Qg, Ka, Va, p*64, 0, p+1, true,
               wid, g, c, arow, achk, pbase, cs, mi, li, o);
    {
      float nr = 1.f / li;                  // lane-local (q = c)
      int row = p*64 + wid*16 + c;
      size_t rb = ((size_t)b*2048 + row)*1024 + h*64;
#pragma unroll
      for (int df = 0; df < 4; ++df) {
        u16x4 pk;
        pk[0] = f2bf(o[df][0] * nr); pk[1] = f2bf(o[df][1] * nr);
        pk[2] = f2bf(o[df][2] * nr); pk[3] = f2bf(o[df][3] * nr);
        *(u16x4*)&AO[rb + df*16 + g*4] = pk;
      }
    }
    attn_phase(lds, Qg, Ka, Va, (31-p)*64, 0, 16-p, false,
               wid, g, c, arow, achk, pbase, cs, mi, li, o);
    store_partial(part, slot, 0, wid, g, c, mi, li, o);
  } else {
    attn_phase(lds, Qg, Ka, Va, (31-p)*64, 16-p, 16, true,
               wid, g, c, arow, achk, pbase, cs, mi, li, o);
    store_partial(part, slot, 1, wid, g, c, mi, li, o);
  }
}

// ---------------- merge the two partials of q-tiles 16..31 -----------------------------
__global__ __launch_bounds__(256) void attn_merge(
    const float* __restrict__ part, u16* __restrict__ AO)
{
  int slot = blockIdx.x;            // ((b*16+h)*16+p)
  int p = slot & 15;
  int h = (slot >> 4) & 15;
  int b = slot >> 8;
  const float* p0 = part + (size_t)slot * 8448;
  const float* p1 = p0 + 4224;
  int t = threadIdx.x;
  int r = t >> 2, c0 = (t & 3) * 16;
  float m0 = p0[4096 + r], m1 = p1[4096 + r];
  float l0 = p0[4160 + r], l1 = p1[4160 + r];
  float m = fmaxf(m0, m1);
  float e0 = exp2f(m0 - m), e1 = exp2f(m1 - m);
  float rl = 1.f / (l0*e0 + l1*e1);
  e0 *= rl; e1 *= rl;
  const f32x4* a0 = (const f32x4*)(p0 + r*64 + c0);
  const f32x4* a1 = (const f32x4*)(p1 + r*64 + c0);
  u16x8 w0, w1;
#pragma unroll
  for (int q4 = 0; q4 < 4; ++q4) {
    f32x4 x = a0[q4], y = a1[q4];
#pragma unroll
    for (int j = 0; j < 4; ++j) {
      u16 bf = f2bf(x[j]*e0 + y[j]*e1);
      if (q4 < 2) w0[q4*4+j] = bf; else w1[(q4-2)*4+j] = bf;
    }
  }
  int qrow = (31 - p)*64 + r;
  size_t ab = ((size_t)b*2048 + qrow)*1024 + h*64 + c0;
  *(u16x8*)&AO[ab]     = w0;
  *(u16x8*)&AO[ab + 8] = w1;
}

// ---------------------------------------------------------------------------------------
extern "C" void kernel_launch(void* const* d_in, const int* in_sizes, int n_in,
                              void* d_out, int out_size, void* d_ws, size_t ws_size,
                              hipStream_t stream)
{
  const float* q  = (const float*)d_in[0];
  const float* k  = (const float*)d_in[1];
  const float* v  = (const float*)d_in[2];
  // d_in[3] = mask (causal tril; applied analytically)
  const float* Wq = (const float*)d_in[4];
  const float* bq = (const float*)d_in[5];
  const float* Wk = (const float*)d_in[6];
  const float* bk = (const float*)d_in[7];
  const float* Wv = (const float*)d_in[8];
  const float* bv = (const float*)d_in[9];
  const float* Wo = (const float*)d_in[10];
  const float* bo = (const float*)d_in[11];
  float* out = (float*)d_out;

  u16* ws   = (u16*)d_ws;
  u16* qb   = ws;                 // [3][4096][1024] bf16 inputs (dead after gemm_qkv;
                                  //  reused as f32 partial buffer by attn)
  u16* Wqb  = ws + 12582912;      // [3][1024][1024] bf16 weights (Wq,Wk,Wv)
  u16* Wob  = ws + 15728640;      // [1024][1024]
  u16* QKp  = ws + 16777216;      // [4096][2048]  (Q | K)
  u16* VTp  = ws + 25165824;      // [2][16][64][2048]  V transposed
  u16* AO   = ws + 29360128;      // [4096][1024]   (total = 64 MB exactly)

  convert_all<<<8192, 256, 0, stream>>>(q, k, v, Wq, Wk, Wv, Wo, qb);

  gemm_qkv<<<192, 512, 0, stream>>>(qb, Wqb, bq, bk, bv, QKp, VTp);

  attn_fwd<<<1024, 256, 0, stream>>>(QKp, VTp, AO, (float*)d_ws);

  attn_merge<<<512, 256, 0, stream>>>((const float*)d_ws, AO);

  dim3 g1(16, 32);
  gemm_out<<<g1, 256, 0, stream>>>(AO, Wob, bo, out);
}

// Round 9
// 109.024 us; speedup vs baseline: 1.2116x; 1.0522x over previous
//
#include <hip/hip_runtime.h>

typedef unsigned int u32;
typedef unsigned short u16;
typedef __attribute__((ext_vector_type(8))) short bf16x8;
typedef __attribute__((ext_vector_type(8))) u16 u16x8;
typedef __attribute__((ext_vector_type(4))) u16 u16x4;
typedef __attribute__((ext_vector_type(4))) float f32x4;
typedef __attribute__((ext_vector_type(2))) u32 u32x2;

#define AS1 __attribute__((address_space(1)))
#define AS3 __attribute__((address_space(3)))

__device__ __forceinline__ void gload_lds16(const void* g, void* l) {
  __builtin_amdgcn_global_load_lds((const AS1 u32*)g, (AS3 u32*)l, 16, 0, 0);
}

__device__ __forceinline__ u16 f2bf(float f) {
  union { float f; u32 u; } x; x.f = f;
  u32 u = x.u;
  return (u16)((u + 0x7fffu + ((u >> 16) & 1u)) >> 16);
}

__device__ __forceinline__ u32 cvt_pk_bf16(float lo, float hi) {
  u32 r;
  asm("v_cvt_pk_bf16_f32 %0, %1, %2" : "=v"(r) : "v"(lo), "v"(hi));
  return r;
}

__device__ __forceinline__ float fexp2(float x) {
  float r;
  asm("v_exp_f32 %0, %1" : "=v"(r) : "v"(x));
  return r;
}

// ---------------- convert fp32 -> bf16 (q,k,v,Wq,Wk,Wv,Wo packed contiguously) ---------
__global__ __launch_bounds__(256) void convert_all(
    const float* __restrict__ q, const float* __restrict__ k, const float* __restrict__ v,
    const float* __restrict__ wq, const float* __restrict__ wk,
    const float* __restrict__ wv, const float* __restrict__ wo,
    u16* __restrict__ dst)
{
  int b = blockIdx.x, t = threadIdx.x;
  const float* sp; size_t lb;
  if (b < 6144) {
    sp = (b < 2048) ? q : ((b < 4096) ? k : v);
    lb = (size_t)(b & 2047) * 2048;
  } else {
    int w = (b - 6144) >> 9;
    sp = (w == 0) ? wq : ((w == 1) ? wk : ((w == 2) ? wv : wo));
    lb = (size_t)((b - 6144) & 511) * 2048;
  }
  lb += (size_t)t * 8;
  f32x4 f0 = *(const f32x4*)(sp + lb);
  f32x4 f1 = *(const f32x4*)(sp + lb + 4);
  u16x8 o;
  o[0]=f2bf(f0[0]); o[1]=f2bf(f0[1]); o[2]=f2bf(f0[2]); o[3]=f2bf(f0[3]);
  o[4]=f2bf(f1[0]); o[5]=f2bf(f1[1]); o[6]=f2bf(f1[2]); o[7]=f2bf(f1[3]);
  *(u16x8*)(dst + (size_t)b*2048 + (size_t)t*8) = o;
}

// ---------------- fused QKV GEMM, 128x128 tile, BK=32, ring-3, 768 blocks --------------
// 256 threads = 4 waves (2x2), wave tile 64x64 (acc[4][4]). LDS 48 KB (3 ring bufs x
// (A 8KB + B 8KB)) -> 3 blocks/CU; grid 768 = 3*256 exactly. stage(t+2) into a buffer
// nobody reads; counted vmcnt(4). XCD-chunked (768%8==0, bijective).
__global__ __launch_bounds__(256, 3) void gemm_qkv(
    const u16* __restrict__ Xall,   // [3][4096][1024] bf16 (q,k,v)
    const u16* __restrict__ Wall,   // [3][1024][1024] bf16 (Wq,Wk,Wv)
    const float* __restrict__ bq, const float* __restrict__ bk, const float* __restrict__ bv,
    u16* __restrict__ Cqk, u16* __restrict__ VT)
{
  __shared__ __align__(16) u16 lds[24576];   // 3 x 8192 u16 (A:[0,4096) B:[4096,8192))
  const int t = threadIdx.x;
  const int wid = t >> 6, l = t & 63;
  const int c = l & 15, g = l >> 4;
  const int u = blockIdx.x;
  const int lid = (u & 7) * 96 + (u >> 3);
  const int which = lid >> 8;               // 256 tiles per which
  const int r5 = lid & 255;
  const int m0 = (r5 >> 3) * 128, n0 = (r5 & 7) * 128;
  const u16* A  = Xall + (size_t)which * 4194304;
  const u16* Bw = Wall + (size_t)which * 1048576;
  const int wr = wid >> 1, wc = wid & 1;

  // staging: wave wid pass j covers rows (wid + j*4)*16 .. +15, lane l -> row_off l>>2,
  // chunk l&3; source pre-swizzled so linear LDS dest holds swizzled content.
  const int srow = wid*16 + (l >> 2);
  const int sswz = ((l & 3) ^ (srow & 3) ^ ((srow >> 2) & 3)) << 3;
  const u16* Asrc0 = A  + (size_t)(m0 + srow)*1024      + sswz;
  const u16* Asrc1 = A  + (size_t)(m0 + 64 + srow)*1024 + sswz;
  const u16* Bsrc0 = Bw + (size_t)(n0 + srow)*1024      + sswz;
  const u16* Bsrc1 = Bw + (size_t)(n0 + 64 + srow)*1024 + sswz;
  const int wbase = wid * 512;              // u16 units (1 KB per wave-pass)

#define QKV_STAGE(j) do { \
    const int bo_ = ((j) % 3) * 8192; const int ko_ = (j) << 5; \
    gload_lds16(Asrc0 + ko_, &lds[bo_ + wbase]); \
    gload_lds16(Asrc1 + ko_, &lds[bo_ + 2048 + wbase]); \
    gload_lds16(Bsrc0 + ko_, &lds[bo_ + 4096 + wbase]); \
    gload_lds16(Bsrc1 + ko_, &lds[bo_ + 6144 + wbase]); \
  } while (0)

  // frag reads: read-side swizzle matches source swizzle (row bits 0..3 == c)
  const int fswz = (g ^ (c & 3) ^ ((c >> 2) & 3)) << 3;
  const int abase = (wr*64 + c)*32 + fswz;          // + mf*512
  const int bbase = 4096 + (wc*64 + c)*32 + fswz;   // + nf*512

  f32x4 acc[4][4] = {};

  QKV_STAGE(0);
  QKV_STAGE(1);
  asm volatile("s_waitcnt vmcnt(4)" ::: "memory");
  __builtin_amdgcn_s_barrier();
  __builtin_amdgcn_sched_barrier(0);

#pragma unroll
  for (int tstep = 0; tstep < 32; ++tstep) {
    if (tstep + 2 < 32) QKV_STAGE(tstep + 2);
    const int bo = (tstep % 3) * 8192;
    bf16x8 af[4], bf[4];
#pragma unroll
    for (int mf = 0; mf < 4; ++mf)
      af[mf] = *(const bf16x8*)&lds[bo + abase + mf*512];
#pragma unroll
    for (int nf = 0; nf < 4; ++nf)
      bf[nf] = *(const bf16x8*)&lds[bo + bbase + nf*512];
    __builtin_amdgcn_s_setprio(1);
#pragma unroll
    for (int mf = 0; mf < 4; ++mf)
#pragma unroll
      for (int nf = 0; nf < 4; ++nf)
        acc[mf][nf] = __builtin_amdgcn_mfma_f32_16x16x32_bf16(af[mf], bf[nf], acc[mf][nf], 0, 0, 0);
    __builtin_amdgcn_s_setprio(0);
    if (tstep + 2 < 32) asm volatile("s_waitcnt vmcnt(4)" ::: "memory");
    else                asm volatile("s_waitcnt vmcnt(0)" ::: "memory");
    __builtin_amdgcn_s_barrier();
    __builtin_amdgcn_sched_barrier(0);
  }
#undef QKV_STAGE

  const float* bias = (which == 0) ? bq : ((which == 1) ? bk : bv);
  if (which < 2) {
#pragma unroll
    for (int mf = 0; mf < 4; ++mf)
#pragma unroll
      for (int nf = 0; nf < 4; ++nf) {
        int row = m0 + wr*64 + mf*16 + g*4;
        int col = n0 + wc*64 + nf*16 + c;
        float bv_ = bias[col];
        int colg = which*1024 + col;
#pragma unroll
        for (int r = 0; r < 4; ++r)
          Cqk[(size_t)(row+r)*2048 + colg] = f2bf(acc[mf][nf][r] + bv_);
      }
  } else {
#pragma unroll
    for (int mf = 0; mf < 4; ++mf)
#pragma unroll
      for (int nf = 0; nf < 4; ++nf) {
        int row = m0 + wr*64 + mf*16 + g*4;
        int col = n0 + wc*64 + nf*16 + c;
        float bv_ = bias[col];
        int bb2 = row >> 11, s = row & 2047;
        int hh = col >> 6, dh = col & 63;
        u16x4 pk;
#pragma unroll
        for (int r = 0; r < 4; ++r) pk[r] = f2bf(acc[mf][nf][r] + bv_);
        *(u16x4*)&VT[((size_t)(((bb2<<4)+hh)<<6) + dh)*2048 + s] = pk;
      }
  }
}

// ---------------- GEMM: out = AO * Wo^T + bo, fp32 out --------------------------------
__global__ __launch_bounds__(256) void gemm_out(
    const u16* __restrict__ A, const u16* __restrict__ Bw,
    const float* __restrict__ bias, float* __restrict__ C)
{
  __shared__ __align__(16) u16 As[128*64];
  __shared__ __align__(16) u16 Bs[64*64];
  const int t = threadIdx.x;
  const int wid = t >> 6, l = t & 63;
  const int l4 = l >> 4, l15 = l & 15;
  const int m0 = blockIdx.y * 128, n0 = blockIdx.x * 64;
  const int wr = wid >> 1, wc = wid & 1;
  const int arow = t >> 3, achk = t & 7;

  f32x4 acc[4][2] = {};

  for (int k0 = 0; k0 < 1024; k0 += 64) {
    __syncthreads();
#pragma unroll
    for (int i = 0; i < 4; ++i) {
      int row = i*32 + arow;
      gload_lds16(A + (size_t)(m0+row)*1024 + k0 + ((achk ^ (row&7)) << 3),
                  &As[i*2048 + wid*512]);
    }
#pragma unroll
    for (int i = 0; i < 2; ++i) {
      int row = i*32 + arow;
      gload_lds16(Bw + (size_t)(n0+row)*1024 + k0 + ((achk ^ (row&7)) << 3),
                  &Bs[i*2048 + wid*512]);
    }
    __syncthreads();
#pragma unroll
    for (int kh = 0; kh < 2; ++kh) {
      bf16x8 af[4], bf[2];
#pragma unroll
      for (int mf = 0; mf < 4; ++mf) {
        int row = wr*64 + mf*16 + l15;
        int ch = (kh*4 + l4) ^ (row & 7);
        af[mf] = *(const bf16x8*)&As[row*64 + ch*8];
      }
#pragma unroll
      for (int nf = 0; nf < 2; ++nf) {
        int row = wc*32 + nf*16 + l15;
        int ch = (kh*4 + l4) ^ (row & 7);
        bf[nf] = *(const bf16x8*)&Bs[row*64 + ch*8];
      }
#pragma unroll
      for (int mf = 0; mf < 4; ++mf)
#pragma unroll
        for (int nf = 0; nf < 2; ++nf)
          acc[mf][nf] = __builtin_amdgcn_mfma_f32_16x16x32_bf16(af[mf], bf[nf], acc[mf][nf], 0, 0, 0);
    }
  }
#pragma unroll
  for (int mf = 0; mf < 4; ++mf)
#pragma unroll
    for (int nf = 0; nf < 2; ++nf) {
      int row = m0 + wr*64 + mf*16 + l4*4;
      int col = n0 + wc*32 + nf*16 + l15;
      float bv = bias[col];
#pragma unroll
      for (int r = 0; r < 4; ++r)
        C[(size_t)(row+r)*1024 + col] = acc[mf][nf][r] + bv;
    }
}

// ---------------- causal flash attention, split-KV, DH=64, QBLK=64, KVBLK=64 -----------
// Swapped QK^T and swapped PV (all softmax state lane-local). Defer-max (THR=8 in log2
// domain): rescale only when some lane's tile-max exceeds stale m by >8; li kept as
// per-lane partial, reduced across the 4 replica lanes once per phase.
__device__ __forceinline__ void stage_kv(u16* lds, const u16* Kt, const u16* Vt,
                                         int buf, int wid) {
#pragma unroll
  for (int ii = 0; ii < 2; ++ii)
    gload_lds16(Kt + (size_t)ii*32*2048, &lds[4096 + buf*4096 + ii*2048 + wid*512]);
#pragma unroll
  for (int ii = 0; ii < 2; ++ii)
    gload_lds16(Vt + (size_t)ii*32*2048, &lds[12288 + buf*4096 + ii*2048 + wid*512]);
}

__device__ __forceinline__ void attn_phase(
    u16* lds, const u16* Qg, const u16* Ka, const u16* Va,
    int q0, int kt0, int nkv, bool maskLast,
    int wid, int g, int c, int arow, int achk, int pbase, int cs,
    float& MI, float& LI, f32x4 (&o)[4])
{
  const float SC = 0.18033688f;  // (1/8) * log2(e)
  // stage Q tile [64][64] swizzled
#pragma unroll
  for (int i = 0; i < 2; ++i) {
    int row = i*32 + arow;
    gload_lds16(Qg + (size_t)(q0+row)*2048 + ((achk ^ (row&7)) << 3),
                &lds[i*2048 + wid*512]);
  }
  const u16* Kt = Ka + (size_t)kt0 * (64*2048);
  const u16* Vt = Va + kt0 * 64;
  stage_kv(lds, Kt, Vt, 0, wid);
  asm volatile("s_waitcnt vmcnt(0)" ::: "memory");
  __builtin_amdgcn_s_barrier();
  __builtin_amdgcn_sched_barrier(0);

  bf16x8 qf[2];
#pragma unroll
  for (int kh = 0; kh < 2; ++kh) {
    int row = wid*16 + c;
    int ch = (kh*4 + g) ^ (row & 7);
    qf[kh] = *(const bf16x8*)&lds[row*64 + ch*8];
  }

  float mi = -INFINITY, li = 0.f;   // li: per-lane partial (this lane's k-slice)
#pragma unroll
  for (int df = 0; df < 4; ++df) o[df] = f32x4{0.f, 0.f, 0.f, 0.f};

  for (int i = 0; i < nkv; ++i) {
    if (i + 1 < nkv) {
      Kt += 64*2048; Vt += 64;
      stage_kv(lds, Kt, Vt, (i+1)&1, wid);
    }
    const u16* Kb = &lds[4096  + (i&1)*4096];
    const u16* Vb = &lds[12288 + (i&1)*4096];

    // QK^T swapped: lane holds q = c, k = 16nf + 4g + r
    f32x4 sT[4] = {};
    __builtin_amdgcn_s_setprio(1);
#pragma unroll
    for (int kh = 0; kh < 2; ++kh) {
      bf16x8 kf[4];
#pragma unroll
      for (int nf = 0; nf < 4; ++nf) {
        int row = nf*16 + c;
        int ch = (kh*4 + g) ^ (c & 7);
        kf[nf] = *(const bf16x8*)&Kb[row*64 + ch*8];
      }
#pragma unroll
      for (int nf = 0; nf < 4; ++nf)
        sT[nf] = __builtin_amdgcn_mfma_f32_16x16x32_bf16(kf[nf], qf[kh], sT[nf], 0,0,0);
    }
    __builtin_amdgcn_s_setprio(0);

    if (maskLast && i == nkv - 1) {   // diagonal causal mask
#pragma unroll
      for (int nf = 0; nf < 4; ++nf)
#pragma unroll
        for (int r = 0; r < 4; ++r)
          if (nf*16 + g*4 + r > wid*16 + c) sT[nf][r] = -INFINITY;
    }

    // defer-max online softmax: lane-local tile max, rescale only on overflow risk
    float mx = fmaxf(fmaxf(sT[0][0], sT[0][1]), fmaxf(sT[0][2], sT[0][3]));
#pragma unroll
    for (int nf = 1; nf < 4; ++nf)
      mx = fmaxf(mx, fmaxf(fmaxf(sT[nf][0], sT[nf][1]), fmaxf(sT[nf][2], sT[nf][3])));
    if (!__all(mx * SC <= mi + 8.f)) {   // rare path: true online-softmax rescale
      float mxr = fmaxf(mx, __shfl_xor(mx, 16, 64));
      mxr = fmaxf(mxr, __shfl_xor(mxr, 32, 64));
      float mn = fmaxf(mi, mxr * SC);
      float corr = fexp2(mi - mn);
      li *= corr;
#pragma unroll
      for (int df = 0; df < 4; ++df) {
        o[df][0] *= corr; o[df][1] *= corr;
        o[df][2] *= corr; o[df][3] *= corr;
      }
      mi = mn;
    }
    float sum = 0.f;
#pragma unroll
    for (int nf = 0; nf < 4; ++nf)
#pragma unroll
      for (int r = 0; r < 4; ++r) {
        float pv = fexp2(fmaf(sT[nf][r], SC, -mi));
        sT[nf][r] = pv;
        sum += pv;
      }
    li += sum;

    // P -> LDS (wave-private), packed bf16 via cvt_pk + b64 writes
#pragma unroll
    for (int nf = 0; nf < 4; ++nf) {
      u32x2 ww;
      ww[0] = cvt_pk_bf16(sT[nf][0], sT[nf][1]);
      ww[1] = cvt_pk_bf16(sT[nf][2], sT[nf][3]);
      int ch = (2*nf + (g >> 1)) ^ cs;
      *(u32x2*)&lds[pbase + c*64 + ch*8 + (g & 1)*4] = ww;
    }
    asm volatile("s_waitcnt lgkmcnt(0)" ::: "memory");
    __builtin_amdgcn_sched_barrier(0);

    // PV swapped: o[df] = V^T-frag x P-frag -> O^T[d = df*16+4g+r][q = c]
    __builtin_amdgcn_s_setprio(1);
#pragma unroll
    for (int kh = 0; kh < 2; ++kh) {
      bf16x8 pfr, vf[4];
      {
        int ch = (kh*4 + g) ^ cs;
        pfr = *(const bf16x8*)&lds[pbase + c*64 + ch*8];
      }
#pragma unroll
      for (int df = 0; df < 4; ++df) {
        int d = df*16 + c;
        int ch = (kh*4 + g) ^ (d & 7);
        vf[df] = *(const bf16x8*)&Vb[d*64 + ch*8];
      }
#pragma unroll
      for (int df = 0; df < 4; ++df)
        o[df] = __builtin_amdgcn_mfma_f32_16x16x32_bf16(vf[df], pfr, o[df], 0,0,0);
    }
    __builtin_amdgcn_s_setprio(0);

    asm volatile("s_waitcnt vmcnt(0)" ::: "memory");  // next K/V tile landed
    __builtin_amdgcn_s_barrier();                     // all done reading cur bufs
    __builtin_amdgcn_sched_barrier(0);
  }
  MI = mi; LI = li;
}

__device__ __forceinline__ void store_partial(
    float* __restrict__ part, int slot, int s,
    int wid, int g, int c, float mi, float li_tot, const f32x4 (&o)[4])
{
  float* po = part + (size_t)(slot*2 + s) * 4224;
  int q = wid*16 + c;
#pragma unroll
  for (int df = 0; df < 4; ++df)
    *(f32x4*)&po[q*64 + df*16 + g*4] = o[df];
  if (g == 0) { po[4096 + q] = mi; po[4160 + q] = li_tot; }
}

__global__ __launch_bounds__(256, 4) void attn_fwd(
    const u16* __restrict__ QK, const u16* __restrict__ VT,
    u16* __restrict__ AO, float* __restrict__ part)
{
  // u16 units: [0,4096) Q staging / per-wave P; [4096,12288) K dbuf; [12288,20480) V dbuf
  __shared__ __align__(16) u16 lds[20480];
  const int t = threadIdx.x;
  const int wid = t >> 6, l = t & 63;
  const int g = l >> 4, c = l & 15;
  const int u = blockIdx.x;
  const int lid = (u & 7) * 128 + (u >> 3);
  const int gx = lid & 31, h = (lid >> 5) & 15, b = lid >> 9;
  const int p = gx >> 1, s = gx & 1;
  const u16* Qg  = QK + (size_t)b * 2048 * 2048 + (size_t)h * 64;
  const u16* Kg  = Qg + 1024;
  const u16* VTg = VT + (size_t)(((b << 4) + h) << 6) * 2048;
  const int arow = t >> 3, achk = t & 7;
  const int pbase = wid * 1024;
  const int cs = (c & 7) ^ ((c >> 3) << 2);
  const u16* Ka = Kg  + (size_t)arow*2048 + ((achk ^ (arow & 7)) << 3);
  const u16* Va = VTg + (size_t)arow*2048 + ((achk ^ (arow & 7)) << 3);
  const int slot = ((b*16 + h)*16 + p);

  float mi, li; f32x4 o[4];

  if (s == 0) {
    attn_phase(lds, Qg, Ka, Va, p*64, 0, p+1, true,
               wid, g, c, arow, achk, pbase, cs, mi, li, o);
    {
      float lt = li + __shfl_xor(li, 16, 64);
      lt += __shfl_xor(lt, 32, 64);
      float nr = 1.f / lt;                  // lane-local (q = c)
      int row = p*64 + wid*16 + c;
      size_t rb = ((size_t)b*2048 + row)*1024 + h*64;
#pragma unroll
      for (int df = 0; df < 4; ++df) {
        u16x4 pk;
        pk[0] = f2bf(o[df][0] * nr); pk[1] = f2bf(o[df][1] * nr);
        pk[2] = f2bf(o[df][2] * nr); pk[3] = f2bf(o[df][3] * nr);
        *(u16x4*)&AO[rb + df*16 + g*4] = pk;
      }
    }
    attn_phase(lds, Qg, Ka, Va, (31-p)*64, 0, 16-p, false,
               wid, g, c, arow, achk, pbase, cs, mi, li, o);
    float lt = li + __shfl_xor(li, 16, 64);
    lt += __shfl_xor(lt, 32, 64);
    store_partial(part, slot, 0, wid, g, c, mi, lt, o);
  } else {
    attn_phase(lds, Qg, Ka, Va, (31-p)*64, 16-p, 16, true,
               wid, g, c, arow, achk, pbase, cs, mi, li, o);
    float lt = li + __shfl_xor(li, 16, 64);
    lt += __shfl_xor(lt, 32, 64);
    store_partial(part, slot, 1, wid, g, c, mi, lt, o);
  }
}

// ---------------- merge the two partials of q-tiles 16..31 -----------------------------
__global__ __launch_bounds__(256) void attn_merge(
    const float* __restrict__ part, u16* __restrict__ AO)
{
  int slot = blockIdx.x;            // ((b*16+h)*16+p)
  int p = slot & 15;
  int h = (slot >> 4) & 15;
  int b = slot >> 8;
  const float* p0 = part + (size_t)slot * 8448;
  const float* p1 = p0 + 4224;
  int t = threadIdx.x;
  int r = t >> 2, c0 = (t & 3) * 16;
  float m0 = p0[4096 + r], m1 = p1[4096 + r];
  float l0 = p0[4160 + r], l1 = p1[4160 + r];
  float m = fmaxf(m0, m1);
  float e0 = exp2f(m0 - m), e1 = exp2f(m1 - m);
  float rl = 1.f / (l0*e0 + l1*e1);
  e0 *= rl; e1 *= rl;
  const f32x4* a0 = (const f32x4*)(p0 + r*64 + c0);
  const f32x4* a1 = (const f32x4*)(p1 + r*64 + c0);
  u16x8 w0, w1;
#pragma unroll
  for (int q4 = 0; q4 < 4; ++q4) {
    f32x4 x = a0[q4], y = a1[q4];
#pragma unroll
    for (int j = 0; j < 4; ++j) {
      u16 bf = f2bf(x[j]*e0 + y[j]*e1);
      if (q4 < 2) w0[q4*4+j] = bf; else w1[(q4-2)*4+j] = bf;
    }
  }
  int qrow = (31 - p)*64 + r;
  size_t ab = ((size_t)b*2048 + qrow)*1024 + h*64 + c0;
  *(u16x8*)&AO[ab]     = w0;
  *(u16x8*)&AO[ab + 8] = w1;
}

// ---------------------------------------------------------------------------------------
extern "C" void kernel_launch(void* const* d_in, const int* in_sizes, int n_in,
                              void* d_out, int out_size, void* d_ws, size_t ws_size,
                              hipStream_t stream)
{
  const float* q  = (const float*)d_in[0];
  const float* k  = (const float*)d_in[1];
  const float* v  = (const float*)d_in[2];
  // d_in[3] = mask (causal tril; applied analytically)
  const float* Wq = (const float*)d_in[4];
  const float* bq = (const float*)d_in[5];
  const float* Wk = (const float*)d_in[6];
  const float* bk = (const float*)d_in[7];
  const float* Wv = (const float*)d_in[8];
  const float* bv = (const float*)d_in[9];
  const float* Wo = (const float*)d_in[10];
  const float* bo = (const float*)d_in[11];
  float* out = (float*)d_out;

  u16* ws   = (u16*)d_ws;
  u16* qb   = ws;                 // [3][4096][1024] bf16 inputs (dead after gemm_qkv;
                                  //  reused as f32 partial buffer by attn)
  u16* Wqb  = ws + 12582912;      // [3][1024][1024] bf16 weights (Wq,Wk,Wv)
  u16* Wob  = ws + 15728640;      // [1024][1024]
  u16* QKp  = ws + 16777216;      // [4096][2048]  (Q | K)
  u16* VTp  = ws + 25165824;      // [2][16][64][2048]  V transposed
  u16* AO   = ws + 29360128;      // [4096][1024]   (total = 64 MB exactly)

  convert_all<<<8192, 256, 0, stream>>>(q, k, v, Wq, Wk, Wv, Wo, qb);

  gemm_qkv<<<768, 256, 0, stream>>>(qb, Wqb, bq, bk, bv, QKp, VTp);

  attn_fwd<<<1024, 256, 0, stream>>>(QKp, VTp, AO, (float*)d_ws);

  attn_merge<<<512, 256, 0, stream>>>((const float*)d_ws, AO);

  dim3 g1(16, 32);
  gemm_out<<<g1, 256, 0, stream>>>(AO, Wob, bo, out);
}

// Round 10
// 101.819 us; speedup vs baseline: 1.2974x; 1.0708x over previous
//
#include <hip/hip_runtime.h>

typedef unsigned int u32;
typedef unsigned short u16;
typedef __attribute__((ext_vector_type(8))) short bf16x8;
typedef __attribute__((ext_vector_type(8))) u16 u16x8;
typedef __attribute__((ext_vector_type(4))) u16 u16x4;
typedef __attribute__((ext_vector_type(4))) float f32x4;
typedef __attribute__((ext_vector_type(2))) u32 u32x2;

#define AS1 __attribute__((address_space(1)))
#define AS3 __attribute__((address_space(3)))

__device__ __forceinline__ void gload_lds16(const void* g, void* l) {
  __builtin_amdgcn_global_load_lds((const AS1 u32*)g, (AS3 u32*)l, 16, 0, 0);
}

__device__ __forceinline__ u16 f2bf(float f) {
  union { float f; u32 u; } x; x.f = f;
  u32 u = x.u;
  return (u16)((u + 0x7fffu + ((u >> 16) & 1u)) >> 16);
}

__device__ __forceinline__ u32 cvt_pk_bf16(float lo, float hi) {
  u32 r;
  asm("v_cvt_pk_bf16_f32 %0, %1, %2" : "=v"(r) : "v"(lo), "v"(hi));
  return r;
}

__device__ __forceinline__ float fexp2(float x) {
  float r;
  asm("v_exp_f32 %0, %1" : "=v"(r) : "v"(x));
  return r;
}

// ---------------- convert fp32 -> bf16, WEIGHTS ONLY (Wq,Wk,Wv,Wo) ---------------------
__global__ __launch_bounds__(256) void convert_w(
    const float* __restrict__ wq, const float* __restrict__ wk,
    const float* __restrict__ wv, const float* __restrict__ wo,
    u16* __restrict__ dst)   // = Wqb base
{
  int b = blockIdx.x, t = threadIdx.x;
  int w = b >> 9;
  const float* sp = (w == 0) ? wq : ((w == 1) ? wk : ((w == 2) ? wv : wo));
  size_t lb = (size_t)(b & 511) * 2048 + (size_t)t * 8;
  f32x4 f0 = *(const f32x4*)(sp + lb);
  f32x4 f1 = *(const f32x4*)(sp + lb + 4);
  u16x8 o;
  o[0]=f2bf(f0[0]); o[1]=f2bf(f0[1]); o[2]=f2bf(f0[2]); o[3]=f2bf(f0[3]);
  o[4]=f2bf(f1[0]); o[5]=f2bf(f1[1]); o[6]=f2bf(f1[2]); o[7]=f2bf(f1[3]);
  *(u16x8*)(dst + (size_t)b*2048 + (size_t)t*8) = o;
}

// ---------------- fused QKV GEMM, 128x128, BK=32, ring-3, fp32-A fused convert ---------
// A read fp32 directly from inputs (reg-stage: load -> cvt_pk -> swizzled ds_write,
// issue-early/write-late, vmcnt(2)); B (bf16 weights) via gload_lds ring-3.
// 768 blocks = 3/CU, XCD-chunked. Q,K -> Cqk[4096][2048]; V -> VT[b][h][dh][s].
__global__ __launch_bounds__(256, 3) void gemm_qkv(
    const float* __restrict__ Xq, const float* __restrict__ Xk, const float* __restrict__ Xv,
    const u16* __restrict__ Wall,   // [3][1024][1024] bf16 (Wq,Wk,Wv)
    const float* __restrict__ bq, const float* __restrict__ bk, const float* __restrict__ bv,
    u16* __restrict__ Cqk, u16* __restrict__ VT)
{
  __shared__ __align__(16) u16 lds[24576];   // 3 x 8192 u16 (A:[0,4096) B:[4096,8192))
  const int t = threadIdx.x;
  const int wid = t >> 6, l = t & 63;
  const int c = l & 15, g = l >> 4;
  const int u = blockIdx.x;
  const int lid = (u & 7) * 96 + (u >> 3);
  const int which = lid >> 8;               // 256 tiles per which
  const int r5 = lid & 255;
  const int m0 = (r5 >> 3) * 128, n0 = (r5 & 7) * 128;
  const float* Afp = (which == 0) ? Xq : ((which == 1) ? Xk : Xv);
  const u16* Bw = Wall + (size_t)which * 1048576;
  const int wr = wid >> 1, wc = wid & 1;

  const int srow = wid*16 + (l >> 2);
  const int schk = l & 3;
  const int aswz = ((schk ^ (srow & 3) ^ ((srow >> 2) & 3)) << 3);
  // A fp32 sources (linear; swizzle applied on the LDS write side)
  const float* Ag0 = Afp + (size_t)(m0 + srow)*1024      + schk*8;
  const float* Ag1 = Afp + (size_t)(m0 + 64 + srow)*1024 + schk*8;
  const int awr0 = srow*32 + aswz;
  const int awr1 = (srow + 64)*32 + aswz;
  // B bf16 sources (pre-swizzled global, linear gload_lds dest)
  const int sswz = aswz;
  const u16* Bsrc0 = Bw + (size_t)(n0 + srow)*1024      + sswz;
  const u16* Bsrc1 = Bw + (size_t)(n0 + 64 + srow)*1024 + sswz;
  const int wbase = wid * 512;

  f32x4 ra0, ra1, ra2, ra3;

#define A_LOAD(j) do { \
    const float* ap0_ = Ag0 + ((j) << 5); \
    const float* ap1_ = Ag1 + ((j) << 5); \
    ra0 = *(const f32x4*)ap0_; ra1 = *(const f32x4*)(ap0_ + 4); \
    ra2 = *(const f32x4*)ap1_; ra3 = *(const f32x4*)(ap1_ + 4); \
  } while (0)

#define A_CVT_WRITE(j) do { \
    const int bo_ = ((j) % 3) * 8192; \
    u16x8 w0_, w1_; u32* q0_ = (u32*)&w0_; u32* q1_ = (u32*)&w1_; \
    q0_[0]=cvt_pk_bf16(ra0[0],ra0[1]); q0_[1]=cvt_pk_bf16(ra0[2],ra0[3]); \
    q0_[2]=cvt_pk_bf16(ra1[0],ra1[1]); q0_[3]=cvt_pk_bf16(ra1[2],ra1[3]); \
    q1_[0]=cvt_pk_bf16(ra2[0],ra2[1]); q1_[1]=cvt_pk_bf16(ra2[2],ra2[3]); \
    q1_[2]=cvt_pk_bf16(ra3[0],ra3[1]); q1_[3]=cvt_pk_bf16(ra3[2],ra3[3]); \
    *(u16x8*)&lds[bo_ + awr0] = w0_; \
    *(u16x8*)&lds[bo_ + awr1] = w1_; \
  } while (0)

#define B_STAGE(j) do { \
    const int bo_ = ((j) % 3) * 8192; const int ko_ = (j) << 5; \
    gload_lds16(Bsrc0 + ko_, &lds[bo_ + 4096 + wbase]); \
    gload_lds16(Bsrc1 + ko_, &lds[bo_ + 6144 + wbase]); \
  } while (0)

  const int fswz = (g ^ (c & 3) ^ ((c >> 2) & 3)) << 3;
  const int abase = (wr*64 + c)*32 + fswz;          // + mf*512
  const int bbase = 4096 + (wc*64 + c)*32 + fswz;   // + nf*512

  f32x4 acc[4][4] = {};

  // prologue
  A_LOAD(0);
  B_STAGE(0);
  B_STAGE(1);
  asm volatile("s_waitcnt vmcnt(2)" ::: "memory");   // A(0), B(0) landed
  A_CVT_WRITE(0);
  A_LOAD(1);
  asm volatile("s_waitcnt lgkmcnt(0)" ::: "memory");
  __builtin_amdgcn_s_barrier();
  __builtin_amdgcn_sched_barrier(0);

#pragma unroll
  for (int tstep = 0; tstep < 32; ++tstep) {
    if (tstep + 2 < 32) B_STAGE(tstep + 2);
    const int bo = (tstep % 3) * 8192;
    bf16x8 af[4], bf[4];
#pragma unroll
    for (int mf = 0; mf < 4; ++mf)
      af[mf] = *(const bf16x8*)&lds[bo + abase + mf*512];
#pragma unroll
    for (int nf = 0; nf < 4; ++nf)
      bf[nf] = *(const bf16x8*)&lds[bo + bbase + nf*512];
    __builtin_amdgcn_s_setprio(1);
#pragma unroll
    for (int mf = 0; mf < 4; ++mf)
#pragma unroll
      for (int nf = 0; nf < 4; ++nf)
        acc[mf][nf] = __builtin_amdgcn_mfma_f32_16x16x32_bf16(af[mf], bf[nf], acc[mf][nf], 0, 0, 0);
    __builtin_amdgcn_s_setprio(0);
    if (tstep + 1 < 32) {
      if (tstep + 2 < 32) asm volatile("s_waitcnt vmcnt(2)" ::: "memory");
      else                asm volatile("s_waitcnt vmcnt(0)" ::: "memory");
      A_CVT_WRITE(tstep + 1);
      if (tstep + 2 < 32) A_LOAD(tstep + 2);
    }
    asm volatile("s_waitcnt lgkmcnt(0)" ::: "memory");
    __builtin_amdgcn_s_barrier();
    __builtin_amdgcn_sched_barrier(0);
  }
#undef A_LOAD
#undef A_CVT_WRITE
#undef B_STAGE

  const float* bias = (which == 0) ? bq : ((which == 1) ? bk : bv);
  if (which < 2) {
#pragma unroll
    for (int mf = 0; mf < 4; ++mf)
#pragma unroll
      for (int nf = 0; nf < 4; ++nf) {
        int row = m0 + wr*64 + mf*16 + g*4;
        int col = n0 + wc*64 + nf*16 + c;
        float bv_ = bias[col];
        int colg = which*1024 + col;
#pragma unroll
        for (int r = 0; r < 4; ++r)
          Cqk[(size_t)(row+r)*2048 + colg] = f2bf(acc[mf][nf][r] + bv_);
      }
  } else {
#pragma unroll
    for (int mf = 0; mf < 4; ++mf)
#pragma unroll
      for (int nf = 0; nf < 4; ++nf) {
        int row = m0 + wr*64 + mf*16 + g*4;
        int col = n0 + wc*64 + nf*16 + c;
        float bv_ = bias[col];
        int bb2 = row >> 11, s = row & 2047;
        int hh = col >> 6, dh = col & 63;
        u16x4 pk;
#pragma unroll
        for (int r = 0; r < 4; ++r) pk[r] = f2bf(acc[mf][nf][r] + bv_);
        *(u16x4*)&VT[((size_t)(((bb2<<4)+hh)<<6) + dh)*2048 + s] = pk;
      }
  }
}

// ---------------- GEMM out = AO * Wo^T + bo, 128x128, BK=32, ring-3, fp32 out ----------
// 256 blocks (1/CU), XCD-chunked; both operands bf16 via gload_lds.
__global__ __launch_bounds__(256, 3) void gemm_out(
    const u16* __restrict__ A, const u16* __restrict__ Bw,
    const float* __restrict__ bias, float* __restrict__ C)
{
  __shared__ __align__(16) u16 lds[24576];
  const int t = threadIdx.x;
  const int wid = t >> 6, l = t & 63;
  const int c = l & 15, g = l >> 4;
  const int u = blockIdx.x;
  const int lid = (u & 7) * 32 + (u >> 3);
  const int m0 = (lid >> 3) * 128, n0 = (lid & 7) * 128;
  const int wr = wid >> 1, wc = wid & 1;

  const int srow = wid*16 + (l >> 2);
  const int sswz = (((l & 3) ^ (srow & 3) ^ ((srow >> 2) & 3)) << 3);
  const u16* Asrc0 = A  + (size_t)(m0 + srow)*1024      + sswz;
  const u16* Asrc1 = A  + (size_t)(m0 + 64 + srow)*1024 + sswz;
  const u16* Bsrc0 = Bw + (size_t)(n0 + srow)*1024      + sswz;
  const u16* Bsrc1 = Bw + (size_t)(n0 + 64 + srow)*1024 + sswz;
  const int wbase = wid * 512;

#define O_STAGE(j) do { \
    const int bo_ = ((j) % 3) * 8192; const int ko_ = (j) << 5; \
    gload_lds16(Asrc0 + ko_, &lds[bo_ + wbase]); \
    gload_lds16(Asrc1 + ko_, &lds[bo_ + 2048 + wbase]); \
    gload_lds16(Bsrc0 + ko_, &lds[bo_ + 4096 + wbase]); \
    gload_lds16(Bsrc1 + ko_, &lds[bo_ + 6144 + wbase]); \
  } while (0)

  const int fswz = (g ^ (c & 3) ^ ((c >> 2) & 3)) << 3;
  const int abase = (wr*64 + c)*32 + fswz;
  const int bbase = 4096 + (wc*64 + c)*32 + fswz;

  f32x4 acc[4][4] = {};

  O_STAGE(0);
  O_STAGE(1);
  asm volatile("s_waitcnt vmcnt(4)" ::: "memory");
  __builtin_amdgcn_s_barrier();
  __builtin_amdgcn_sched_barrier(0);

#pragma unroll
  for (int tstep = 0; tstep < 32; ++tstep) {
    if (tstep + 2 < 32) O_STAGE(tstep + 2);
    const int bo = (tstep % 3) * 8192;
    bf16x8 af[4], bf[4];
#pragma unroll
    for (int mf = 0; mf < 4; ++mf)
      af[mf] = *(const bf16x8*)&lds[bo + abase + mf*512];
#pragma unroll
    for (int nf = 0; nf < 4; ++nf)
      bf[nf] = *(const bf16x8*)&lds[bo + bbase + nf*512];
    __builtin_amdgcn_s_setprio(1);
#pragma unroll
    for (int mf = 0; mf < 4; ++mf)
#pragma unroll
      for (int nf = 0; nf < 4; ++nf)
        acc[mf][nf] = __builtin_amdgcn_mfma_f32_16x16x32_bf16(af[mf], bf[nf], acc[mf][nf], 0, 0, 0);
    __builtin_amdgcn_s_setprio(0);
    if (tstep + 2 < 32) asm volatile("s_waitcnt vmcnt(4)" ::: "memory");
    else                asm volatile("s_waitcnt vmcnt(0)" ::: "memory");
    __builtin_amdgcn_s_barrier();
    __builtin_amdgcn_sched_barrier(0);
  }
#undef O_STAGE

#pragma unroll
  for (int mf = 0; mf < 4; ++mf)
#pragma unroll
    for (int nf = 0; nf < 4; ++nf) {
      int row = m0 + wr*64 + mf*16 + g*4;
      int col = n0 + wc*64 + nf*16 + c;
      float bv_ = bias[col];
#pragma unroll
      for (int r = 0; r < 4; ++r)
        C[(size_t)(row+r)*1024 + col] = acc[mf][nf][r] + bv_;
    }
}

// ---------------- causal flash attention, split-KV, DH=64, QBLK=64, KVBLK=64 -----------
// (unchanged from round 9: swapped QK^T + swapped PV, defer-max THR=8, lane-partial li)
__device__ __forceinline__ void stage_kv(u16* lds, const u16* Kt, const u16* Vt,
                                         int buf, int wid) {
#pragma unroll
  for (int ii = 0; ii < 2; ++ii)
    gload_lds16(Kt + (size_t)ii*32*2048, &lds[4096 + buf*4096 + ii*2048 + wid*512]);
#pragma unroll
  for (int ii = 0; ii < 2; ++ii)
    gload_lds16(Vt + (size_t)ii*32*2048, &lds[12288 + buf*4096 + ii*2048 + wid*512]);
}

__device__ __forceinline__ void attn_phase(
    u16* lds, const u16* Qg, const u16* Ka, const u16* Va,
    int q0, int kt0, int nkv, bool maskLast,
    int wid, int g, int c, int arow, int achk, int pbase, int cs,
    float& MI, float& LI, f32x4 (&o)[4])
{
  const float SC = 0.18033688f;  // (1/8) * log2(e)
#pragma unroll
  for (int i = 0; i < 2; ++i) {
    int row = i*32 + arow;
    gload_lds16(Qg + (size_t)(q0+row)*2048 + ((achk ^ (row&7)) << 3),
                &lds[i*2048 + wid*512]);
  }
  const u16* Kt = Ka + (size_t)kt0 * (64*2048);
  const u16* Vt = Va + kt0 * 64;
  stage_kv(lds, Kt, Vt, 0, wid);
  asm volatile("s_waitcnt vmcnt(0)" ::: "memory");
  __builtin_amdgcn_s_barrier();
  __builtin_amdgcn_sched_barrier(0);

  bf16x8 qf[2];
#pragma unroll
  for (int kh = 0; kh < 2; ++kh) {
    int row = wid*16 + c;
    int ch = (kh*4 + g) ^ (row & 7);
    qf[kh] = *(const bf16x8*)&lds[row*64 + ch*8];
  }

  float mi = -INFINITY, li = 0.f;
#pragma unroll
  for (int df = 0; df < 4; ++df) o[df] = f32x4{0.f, 0.f, 0.f, 0.f};

  for (int i = 0; i < nkv; ++i) {
    if (i + 1 < nkv) {
      Kt += 64*2048; Vt += 64;
      stage_kv(lds, Kt, Vt, (i+1)&1, wid);
    }
    const u16* Kb = &lds[4096  + (i&1)*4096];
    const u16* Vb = &lds[12288 + (i&1)*4096];

    f32x4 sT[4] = {};
    __builtin_amdgcn_s_setprio(1);
#pragma unroll
    for (int kh = 0; kh < 2; ++kh) {
      bf16x8 kf[4];
#pragma unroll
      for (int nf = 0; nf < 4; ++nf) {
        int row = nf*16 + c;
        int ch = (kh*4 + g) ^ (c & 7);
        kf[nf] = *(const bf16x8*)&Kb[row*64 + ch*8];
      }
#pragma unroll
      for (int nf = 0; nf < 4; ++nf)
        sT[nf] = __builtin_amdgcn_mfma_f32_16x16x32_bf16(kf[nf], qf[kh], sT[nf], 0,0,0);
    }
    __builtin_amdgcn_s_setprio(0);

    if (maskLast && i == nkv - 1) {
#pragma unroll
      for (int nf = 0; nf < 4; ++nf)
#pragma unroll
        for (int r = 0; r < 4; ++r)
          if (nf*16 + g*4 + r > wid*16 + c) sT[nf][r] = -INFINITY;
    }

    float mx = fmaxf(fmaxf(sT[0][0], sT[0][1]), fmaxf(sT[0][2], sT[0][3]));
#pragma unroll
    for (int nf = 1; nf < 4; ++nf)
      mx = fmaxf(mx, fmaxf(fmaxf(sT[nf][0], sT[nf][1]), fmaxf(sT[nf][2], sT[nf][3])));
    if (!__all(mx * SC <= mi + 8.f)) {
      float mxr = fmaxf(mx, __shfl_xor(mx, 16, 64));
      mxr = fmaxf(mxr, __shfl_xor(mxr, 32, 64));
      float mn = fmaxf(mi, mxr * SC);
      float corr = fexp2(mi - mn);
      li *= corr;
#pragma unroll
      for (int df = 0; df < 4; ++df) {
        o[df][0] *= corr; o[df][1] *= corr;
        o[df][2] *= corr; o[df][3] *= corr;
      }
      mi = mn;
    }
    float sum = 0.f;
#pragma unroll
    for (int nf = 0; nf < 4; ++nf)
#pragma unroll
      for (int r = 0; r < 4; ++r) {
        float pv = fexp2(fmaf(sT[nf][r], SC, -mi));
        sT[nf][r] = pv;
        sum += pv;
      }
    li += sum;

#pragma unroll
    for (int nf = 0; nf < 4; ++nf) {
      u32x2 ww;
      ww[0] = cvt_pk_bf16(sT[nf][0], sT[nf][1]);
      ww[1] = cvt_pk_bf16(sT[nf][2], sT[nf][3]);
      int ch = (2*nf + (g >> 1)) ^ cs;
      *(u32x2*)&lds[pbase + c*64 + ch*8 + (g & 1)*4] = ww;
    }
    asm volatile("s_waitcnt lgkmcnt(0)" ::: "memory");
    __builtin_amdgcn_sched_barrier(0);

    __builtin_amdgcn_s_setprio(1);
#pragma unroll
    for (int kh = 0; kh < 2; ++kh) {
      bf16x8 pfr, vf[4];
      {
        int ch = (kh*4 + g) ^ cs;
        pfr = *(const bf16x8*)&lds[pbase + c*64 + ch*8];
      }
#pragma unroll
      for (int df = 0; df < 4; ++df) {
        int d = df*16 + c;
        int ch = (kh*4 + g) ^ (d & 7);
        vf[df] = *(const bf16x8*)&Vb[d*64 + ch*8];
      }
#pragma unroll
      for (int df = 0; df < 4; ++df)
        o[df] = __builtin_amdgcn_mfma_f32_16x16x32_bf16(vf[df], pfr, o[df], 0,0,0);
    }
    __builtin_amdgcn_s_setprio(0);

    asm volatile("s_waitcnt vmcnt(0)" ::: "memory");
    __builtin_amdgcn_s_barrier();
    __builtin_amdgcn_sched_barrier(0);
  }
  MI = mi; LI = li;
}

__device__ __forceinline__ void store_partial(
    float* __restrict__ part, int slot, int s,
    int wid, int g, int c, float mi, float li_tot, const f32x4 (&o)[4])
{
  float* po = part + (size_t)(slot*2 + s) * 4224;
  int q = wid*16 + c;
#pragma unroll
  for (int df = 0; df < 4; ++df)
    *(f32x4*)&po[q*64 + df*16 + g*4] = o[df];
  if (g == 0) { po[4096 + q] = mi; po[4160 + q] = li_tot; }
}

__global__ __launch_bounds__(256, 4) void attn_fwd(
    const u16* __restrict__ QK, const u16* __restrict__ VT,
    u16* __restrict__ AO, float* __restrict__ part)
{
  __shared__ __align__(16) u16 lds[20480];
  const int t = threadIdx.x;
  const int wid = t >> 6, l = t & 63;
  const int g = l >> 4, c = l & 15;
  const int u = blockIdx.x;
  const int lid = (u & 7) * 128 + (u >> 3);
  const int gx = lid & 31, h = (lid >> 5) & 15, b = lid >> 9;
  const int p = gx >> 1, s = gx & 1;
  const u16* Qg  = QK + (size_t)b * 2048 * 2048 + (size_t)h * 64;
  const u16* Kg  = Qg + 1024;
  const u16* VTg = VT + (size_t)(((b << 4) + h) << 6) * 2048;
  const int arow = t >> 3, achk = t & 7;
  const int pbase = wid * 1024;
  const int cs = (c & 7) ^ ((c >> 3) << 2);
  const u16* Ka = Kg  + (size_t)arow*2048 + ((achk ^ (arow & 7)) << 3);
  const u16* Va = VTg + (size_t)arow*2048 + ((achk ^ (arow & 7)) << 3);
  const int slot = ((b*16 + h)*16 + p);

  float mi, li; f32x4 o[4];

  if (s == 0) {
    attn_phase(lds, Qg, Ka, Va, p*64, 0, p+1, true,
               wid, g, c, arow, achk, pbase, cs, mi, li, o);
    {
      float lt = li + __shfl_xor(li, 16, 64);
      lt += __shfl_xor(lt, 32, 64);
      float nr = 1.f / lt;
      int row = p*64 + wid*16 + c;
      size_t rb = ((size_t)b*2048 + row)*1024 + h*64;
#pragma unroll
      for (int df = 0; df < 4; ++df) {
        u16x4 pk;
        pk[0] = f2bf(o[df][0] * nr); pk[1] = f2bf(o[df][1] * nr);
        pk[2] = f2bf(o[df][2] * nr); pk[3] = f2bf(o[df][3] * nr);
        *(u16x4*)&AO[rb + df*16 + g*4] = pk;
      }
    }
    attn_phase(lds, Qg, Ka, Va, (31-p)*64, 0, 16-p, false,
               wid, g, c, arow, achk, pbase, cs, mi, li, o);
    float lt = li + __shfl_xor(li, 16, 64);
    lt += __shfl_xor(lt, 32, 64);
    store_partial(part, slot, 0, wid, g, c, mi, lt, o);
  } else {
    attn_phase(lds, Qg, Ka, Va, (31-p)*64, 16-p, 16, true,
               wid, g, c, arow, achk, pbase, cs, mi, li, o);
    float lt = li + __shfl_xor(li, 16, 64);
    lt += __shfl_xor(lt, 32, 64);
    store_partial(part, slot, 1, wid, g, c, mi, lt, o);
  }
}

// ---------------- merge the two partials of q-tiles 16..31 -----------------------------
__global__ __launch_bounds__(256) void attn_merge(
    const float* __restrict__ part, u16* __restrict__ AO)
{
  int slot = blockIdx.x;
  int p = slot & 15;
  int h = (slot >> 4) & 15;
  int b = slot >> 8;
  const float* p0 = part + (size_t)slot * 8448;
  const float* p1 = p0 + 4224;
  int t = threadIdx.x;
  int r = t >> 2, c0 = (t & 3) * 16;
  float m0 = p0[4096 + r], m1 = p1[4096 + r];
  float l0 = p0[4160 + r], l1 = p1[4160 + r];
  float m = fmaxf(m0, m1);
  float e0 = exp2f(m0 - m), e1 = exp2f(m1 - m);
  float rl = 1.f / (l0*e0 + l1*e1);
  e0 *= rl; e1 *= rl;
  const f32x4* a0 = (const f32x4*)(p0 + r*64 + c0);
  const f32x4* a1 = (const f32x4*)(p1 + r*64 + c0);
  u16x8 w0, w1;
#pragma unroll
  for (int q4 = 0; q4 < 4; ++q4) {
    f32x4 x = a0[q4], y = a1[q4];
#pragma unroll
    for (int j = 0; j < 4; ++j) {
      u16 bf = f2bf(x[j]*e0 + y[j]*e1);
      if (q4 < 2) w0[q4*4+j] = bf; else w1[(q4-2)*4+j] = bf;
    }
  }
  int qrow = (31 - p)*64 + r;
  size_t ab = ((size_t)b*2048 + qrow)*1024 + h*64 + c0;
  *(u16x8*)&AO[ab]     = w0;
  *(u16x8*)&AO[ab + 8] = w1;
}

// ---------------------------------------------------------------------------------------
extern "C" void kernel_launch(void* const* d_in, const int* in_sizes, int n_in,
                              void* d_out, int out_size, void* d_ws, size_t ws_size,
                              hipStream_t stream)
{
  const float* q  = (const float*)d_in[0];
  const float* k  = (const float*)d_in[1];
  const float* v  = (const float*)d_in[2];
  // d_in[3] = mask (causal tril; applied analytically)
  const float* Wq = (const float*)d_in[4];
  const float* bq = (const float*)d_in[5];
  const float* Wk = (const float*)d_in[6];
  const float* bk = (const float*)d_in[7];
  const float* Wv = (const float*)d_in[8];
  const float* bv = (const float*)d_in[9];
  const float* Wo = (const float*)d_in[10];
  const float* bo = (const float*)d_in[11];
  float* out = (float*)d_out;

  u16* ws   = (u16*)d_ws;
  // [0 .. 12.6M): attn partial buffer (f32), nothing else uses it now
  u16* Wqb  = ws + 12582912;      // [3][1024][1024] bf16 weights (Wq,Wk,Wv)
  u16* Wob  = ws + 15728640;      // [1024][1024]
  u16* QKp  = ws + 16777216;      // [4096][2048]  (Q | K)
  u16* VTp  = ws + 25165824;      // [2][16][64][2048]  V transposed
  u16* AO   = ws + 29360128;      // [4096][1024]   (total = 64 MB exactly)

  convert_w<<<2048, 256, 0, stream>>>(Wq, Wk, Wv, Wo, Wqb);

  gemm_qkv<<<768, 256, 0, stream>>>(q, k, v, Wqb, bq, bk, bv, QKp, VTp);

  attn_fwd<<<1024, 256, 0, stream>>>(QKp, VTp, AO, (float*)d_ws);

  attn_merge<<<512, 256, 0, stream>>>((const float*)d_ws, AO);

  gemm_out<<<256, 256, 0, stream>>>(AO, Wob, bo, out);
}